// Round 1
// baseline (309.356 us; speedup 1.0000x reference)
//
#include <hip/hip_runtime.h>
#include <hip/hip_bf16.h>
#include <stdint.h>

// Problem constants (B,S,D,H,M) = (2,2048,1024,16,64), HD=64, keys+mem = 2112
#define B_  2
#define S_  2048
#define D_  1024
#define H_  16
#define HD_ 64
#define M_  64
#define SKM (S_ + M_)   // 2112

typedef __attribute__((ext_vector_type(8))) short s16x8;
typedef __attribute__((ext_vector_type(4))) float f32x4;

__device__ __forceinline__ unsigned short f2bf(float f) {
  union { float f; unsigned int u; } v; v.f = f;
  unsigned int r = v.u + 0x7fffu + ((v.u >> 16) & 1u);  // RNE
  return (unsigned short)(r >> 16);
}

// ---------------- f32 -> bf16 conversion (exact-grid, 4 elems/thread) ----------
__global__ void cvt_f32_to_bf16(const float* __restrict__ in,
                                unsigned short* __restrict__ out) {
  int i = (blockIdx.x * blockDim.x + threadIdx.x) * 4;
  float4 v = *(const float4*)&in[i];
  ushort4 o;
  o.x = f2bf(v.x); o.y = f2bf(v.y); o.z = f2bf(v.z); o.w = f2bf(v.w);
  *(ushort4*)&out[i] = o;
}

// ---------------- fill memory K/V rows: K_mem = 8*m_k, V_mem = 8*m_v ----------
__global__ void fill_mem(const float* __restrict__ mk, const float* __restrict__ mv,
                         unsigned short* __restrict__ Kb, unsigned short* __restrict__ Vb) {
  int i = blockIdx.x * 256 + threadIdx.x;     // 0 .. M_*D_-1
  int row = i >> 10, col = i & 1023;
  unsigned short kv = f2bf(8.0f * mk[i]);
  unsigned short vv = f2bf(8.0f * mv[i]);
#pragma unroll
  for (int b = 0; b < B_; b++) {
    size_t o = ((size_t)(b * SKM) + S_ + row) * D_ + col;
    Kb[o] = kv; Vb[o] = vv;
  }
}

// ---------------- GEMM: C = alpha*(A @ Bw^T + bias), A[M][K], Bw[N][K] bf16 ----
// 128x128 tile, BK=32, 4 waves (2x2), per-wave 64x64 = 4x4 mfma_16x16x32_bf16.
// LDS tiles [128][32] with chunk-XOR swizzle (chunk=8 elems, ^= row&3).
template<int OUT_F32>
__global__ __launch_bounds__(256)
void gemm_bt(const unsigned short* __restrict__ A,
             const unsigned short* __restrict__ Bw,
             const float* __restrict__ bias,
             void* __restrict__ Cout,
             int N, int K, float alpha, int rowGap, int rowsPerBatch) {
  __shared__ __align__(16) unsigned short As[128 * 32];
  __shared__ __align__(16) unsigned short Bs[128 * 32];
  const int tid = threadIdx.x;
  const int lane = tid & 63;
  const int w = tid >> 6, wr = w >> 1, wc = w & 1;
  const int lr = lane & 15, lk = lane >> 4;
  const int mBase = blockIdx.y * 128, nBase = blockIdx.x * 128;
  const int r0 = tid >> 2, cb = tid & 3;   // staging: row, 8-elem chunk

  const f32x4 fz = {0.f, 0.f, 0.f, 0.f};
  f32x4 acc[4][4];
#pragma unroll
  for (int i = 0; i < 4; i++)
#pragma unroll
    for (int j = 0; j < 4; j++) acc[i][j] = fz;

  for (int k0 = 0; k0 < K; k0 += 32) {
    uint4 av0 = *(const uint4*)&A[(size_t)(mBase + r0) * K + k0 + cb * 8];
    uint4 av1 = *(const uint4*)&A[(size_t)(mBase + 64 + r0) * K + k0 + cb * 8];
    uint4 bv0 = *(const uint4*)&Bw[(size_t)(nBase + r0) * K + k0 + cb * 8];
    uint4 bv1 = *(const uint4*)&Bw[(size_t)(nBase + 64 + r0) * K + k0 + cb * 8];
    __syncthreads();   // previous tile's reads complete
    *(uint4*)&As[r0 * 32 + ((cb ^ (r0 & 3)) << 3)] = av0;
    *(uint4*)&As[(r0 + 64) * 32 + ((cb ^ (r0 & 3)) << 3)] = av1;
    *(uint4*)&Bs[r0 * 32 + ((cb ^ (r0 & 3)) << 3)] = bv0;
    *(uint4*)&Bs[(r0 + 64) * 32 + ((cb ^ (r0 & 3)) << 3)] = bv1;
    __syncthreads();

    s16x8 af[4], bf[4];
#pragma unroll
    for (int mi = 0; mi < 4; mi++) {
      int row = wr * 64 + mi * 16 + lr;
      af[mi] = *(const s16x8*)&As[row * 32 + ((lk ^ (row & 3)) << 3)];
    }
#pragma unroll
    for (int ni = 0; ni < 4; ni++) {
      int row = wc * 64 + ni * 16 + lr;
      bf[ni] = *(const s16x8*)&Bs[row * 32 + ((lk ^ (row & 3)) << 3)];
    }
#pragma unroll
    for (int mi = 0; mi < 4; mi++)
#pragma unroll
      for (int ni = 0; ni < 4; ni++)
        acc[mi][ni] = __builtin_amdgcn_mfma_f32_16x16x32_bf16(af[mi], bf[ni], acc[mi][ni], 0, 0, 0);
  }

  // C/D layout (m89-verified): col = lane&15, row = (lane>>4)*4 + reg
#pragma unroll
  for (int mi = 0; mi < 4; mi++)
#pragma unroll
    for (int ni = 0; ni < 4; ni++)
#pragma unroll
      for (int r = 0; r < 4; r++) {
        int gr = mBase + wr * 64 + mi * 16 + lk * 4 + r;
        int gc = nBase + wc * 64 + ni * 16 + lr;
        float v = (acc[mi][ni][r] + bias[gc]) * alpha;
        int orow = gr + (gr / rowsPerBatch) * rowGap;   // skip mem rows for K/V
        if (OUT_F32) ((float*)Cout)[(size_t)orow * N + gc] = v;
        else ((unsigned short*)Cout)[(size_t)orow * N + gc] = f2bf(v);
      }
}

// ---------------- Flash attention over 2112 keys, 64-key tiles ----------------
// Block: (q-tile of 64, head, batch); 4 waves x 16 q-rows. Scale 1/8 folded in Q.
__global__ __launch_bounds__(256)
void attn_kernel(const unsigned short* __restrict__ Qb,
                 const unsigned short* __restrict__ Kb,
                 const unsigned short* __restrict__ Vb,
                 const int* __restrict__ mask,
                 unsigned short* __restrict__ Xb) {
  __shared__ __align__(16) unsigned short Ks[64 * 64];       // [key][d] swizzled
  __shared__ __align__(16) unsigned short Vt[64 * 64];       // [d][key] swizzled
  __shared__ __align__(16) unsigned short Ps[4][16 * 64];    // per-wave P [q][key]
  __shared__ int msk[64];

  const int tid = threadIdx.x, lane = tid & 63, w = tid >> 6;
  const int lr = lane & 15, lk = lane >> 4;
  const int qt = blockIdx.x, h = blockIdx.y, b = blockIdx.z;

  // Q fragments (A-operand: row = lane&15, k = 8*(lane>>4)+i)
  size_t qoff = ((size_t)b * S_ + qt * 64 + w * 16 + lr) * D_ + h * HD_;
  s16x8 qf0 = *(const s16x8*)&Qb[qoff + lk * 8];
  s16x8 qf1 = *(const s16x8*)&Qb[qoff + 32 + lk * 8];

  float m_s[4] = {-1e30f, -1e30f, -1e30f, -1e30f};
  float l_s[4] = {0.f, 0.f, 0.f, 0.f};
  const f32x4 fz = {0.f, 0.f, 0.f, 0.f};
  f32x4 accO[4];
#pragma unroll
  for (int n = 0; n < 4; n++) accO[n] = fz;

  const int r0 = tid >> 3, cbk = tid & 7;   // staging: key-row, 8-elem d-chunk

  for (int kt = 0; kt < SKM / 64; ++kt) {
    size_t koff0 = ((size_t)b * SKM + kt * 64 + r0) * D_ + h * HD_ + cbk * 8;
    size_t koff1 = koff0 + (size_t)32 * D_;
    uint4 kv0 = *(const uint4*)&Kb[koff0];
    uint4 kv1 = *(const uint4*)&Kb[koff1];
    uint4 vv0 = *(const uint4*)&Vb[koff0];
    uint4 vv1 = *(const uint4*)&Vb[koff1];
    int mval = 1;
    if (tid < 64) { int key = kt * 64 + tid; mval = (key < S_) ? mask[b * S_ + key] : 1; }
    __syncthreads();   // all waves done reading previous tile
    *(uint4*)&Ks[r0 * 64 + ((cbk ^ (r0 & 7)) << 3)] = kv0;
    *(uint4*)&Ks[(r0 + 32) * 64 + ((cbk ^ (r0 & 7)) << 3)] = kv1;   // (r0+32)&7 == r0&7
    {
      const unsigned short* p0 = (const unsigned short*)&vv0;
      const unsigned short* p1 = (const unsigned short*)&vv1;
#pragma unroll
      for (int j = 0; j < 8; j++) {
        int d = cbk * 8 + j;
        Vt[d * 64 + ((((r0 >> 3) ^ (d & 7)) << 3)) + (r0 & 7)] = p0[j];
        Vt[d * 64 + (((((r0 + 32) >> 3) ^ (d & 7)) << 3)) + (r0 & 7)] = p1[j];
      }
    }
    if (tid < 64) msk[tid] = mval;
    __syncthreads();

    // S = Q·K^T  (16 q x 64 keys per wave), scale already folded into Q
    f32x4 sfr[4];
#pragma unroll
    for (int n = 0; n < 4; n++) {
      int row = n * 16 + lr;
      s16x8 kf0 = *(const s16x8*)&Ks[row * 64 + ((lk ^ (row & 7)) << 3)];
      s16x8 kf1 = *(const s16x8*)&Ks[row * 64 + (((4 + lk) ^ (row & 7)) << 3)];
      f32x4 z = fz;
      z = __builtin_amdgcn_mfma_f32_16x16x32_bf16(qf0, kf0, z, 0, 0, 0);
      z = __builtin_amdgcn_mfma_f32_16x16x32_bf16(qf1, kf1, z, 0, 0, 0);
      sfr[n] = z;
    }
    // mask (col = key = n*16 + (lane&15), same for all 4 regs)
#pragma unroll
    for (int n = 0; n < 4; n++)
      if (!msk[n * 16 + lr]) { sfr[n][0] = -1e30f; sfr[n][1] = -1e30f; sfr[n][2] = -1e30f; sfr[n][3] = -1e30f; }

    // online softmax: rows owned per reg r: q_local = lk*4 + r, reduce over 16 lanes
    float fac[4];
#pragma unroll
    for (int r = 0; r < 4; r++) {
      float vmax = fmaxf(fmaxf(sfr[0][r], sfr[1][r]), fmaxf(sfr[2][r], sfr[3][r]));
#pragma unroll
      for (int off = 1; off < 16; off <<= 1) vmax = fmaxf(vmax, __shfl_xor(vmax, off));
      float mnew = fmaxf(m_s[r], vmax);
      fac[r] = __expf(m_s[r] - mnew);
      float ps = 0.f;
#pragma unroll
      for (int n = 0; n < 4; n++) { float p = __expf(sfr[n][r] - mnew); sfr[n][r] = p; ps += p; }
#pragma unroll
      for (int off = 1; off < 16; off <<= 1) ps += __shfl_xor(ps, off);
      l_s[r] = l_s[r] * fac[r] + ps;
      m_s[r] = mnew;
    }
#pragma unroll
    for (int n = 0; n < 4; n++) {
      accO[n][0] *= fac[0]; accO[n][1] *= fac[1]; accO[n][2] *= fac[2]; accO[n][3] *= fac[3];
    }

    // P -> LDS (bf16), then PV: A-frag from Ps, B-frag from Vt (wave-local, no barrier)
#pragma unroll
    for (int n = 0; n < 4; n++)
#pragma unroll
      for (int r = 0; r < 4; r++) {
        int prow = lk * 4 + r, pcol = n * 16 + lr;
        Ps[w][prow * 64 + (((pcol >> 3) ^ (prow & 7)) << 3) + (pcol & 7)] = f2bf(sfr[n][r]);
      }
#pragma unroll
    for (int kc = 0; kc < 2; kc++) {
      s16x8 pa = *(const s16x8*)&Ps[w][lr * 64 + (((kc * 4 + lk) ^ (lr & 7)) << 3)];
#pragma unroll
      for (int n = 0; n < 4; n++) {
        int vrow = n * 16 + lr;
        s16x8 vb = *(const s16x8*)&Vt[vrow * 64 + (((kc * 4 + lk) ^ (vrow & 7)) << 3)];
        accO[n] = __builtin_amdgcn_mfma_f32_16x16x32_bf16(pa, vb, accO[n], 0, 0, 0);
      }
    }
    // no trailing barrier: next iteration's first __syncthreads() protects LDS
  }

  float inv[4];
#pragma unroll
  for (int r = 0; r < 4; r++) inv[r] = 1.0f / l_s[r];
#pragma unroll
  for (int n = 0; n < 4; n++)
#pragma unroll
    for (int r = 0; r < 4; r++) {
      int row = lk * 4 + r, col = n * 16 + lr;
      size_t o = ((size_t)b * S_ + qt * 64 + w * 16 + row) * D_ + h * HD_ + col;
      Xb[o] = f2bf(accO[n][r] * inv[r]);
    }
}

// ------------------------------- launcher -------------------------------------
extern "C" void kernel_launch(void* const* d_in, const int* in_sizes, int n_in,
                              void* d_out, int out_size, void* d_ws, size_t ws_size,
                              hipStream_t stream) {
  const float* query = (const float*)d_in[0];
  const float* key   = (const float*)d_in[1];
  const float* value = (const float*)d_in[2];
  const int*   mask  = (const int*)d_in[3];
  const float* Wq    = (const float*)d_in[4];
  const float* bq    = (const float*)d_in[5];
  const float* Wk    = (const float*)d_in[6];
  const float* bk    = (const float*)d_in[7];
  const float* Wv    = (const float*)d_in[8];
  const float* bv    = (const float*)d_in[9];
  const float* Wo    = (const float*)d_in[10];
  const float* bo    = (const float*)d_in[11];
  const float* m_k   = (const float*)d_in[12];
  const float* m_v   = (const float*)d_in[13];

  const int NQ = B_ * S_ * D_;     // 4,194,304
  const int NW = D_ * D_;          // 1,048,576
  const int NK = B_ * SKM * D_;    // 4,325,376

  unsigned short* ws = (unsigned short*)d_ws;   // total use: 67.6 MB
  unsigned short* qf = ws;
  unsigned short* kf = qf + NQ;
  unsigned short* vf = kf + NQ;
  unsigned short* wq = vf + NQ;
  unsigned short* wk = wq + NW;
  unsigned short* wv = wk + NW;
  unsigned short* wo = wv + NW;
  unsigned short* Qb = wo + NW;
  unsigned short* Kb = Qb + NQ;
  unsigned short* Vb = Kb + NK;
  unsigned short* Xb = Vb + NK;

  cvt_f32_to_bf16<<<NQ / 1024, 256, 0, stream>>>(query, qf);
  cvt_f32_to_bf16<<<NQ / 1024, 256, 0, stream>>>(key, kf);
  cvt_f32_to_bf16<<<NQ / 1024, 256, 0, stream>>>(value, vf);
  cvt_f32_to_bf16<<<NW / 1024, 256, 0, stream>>>(Wq, wq);
  cvt_f32_to_bf16<<<NW / 1024, 256, 0, stream>>>(Wk, wk);
  cvt_f32_to_bf16<<<NW / 1024, 256, 0, stream>>>(Wv, wv);
  cvt_f32_to_bf16<<<NW / 1024, 256, 0, stream>>>(Wo, wo);
  fill_mem<<<(M_ * D_) / 256, 256, 0, stream>>>(m_k, m_v, Kb, Vb);

  dim3 gg(D_ / 128, (B_ * S_) / 128);   // (8, 32)
  // Q scaled by 1/(sqrt(HD)=8) so attention needs no scale
  gemm_bt<0><<<gg, 256, 0, stream>>>(qf, wq, bq, Qb, D_, D_, 0.125f, 0, S_);
  gemm_bt<0><<<gg, 256, 0, stream>>>(kf, wk, bk, Kb, D_, D_, 1.0f, M_, S_);
  gemm_bt<0><<<gg, 256, 0, stream>>>(vf, wv, bv, Vb, D_, D_, 1.0f, M_, S_);

  attn_kernel<<<dim3(S_ / 64, H_, B_), 256, 0, stream>>>(Qb, Kb, Vb, mask, Xb);

  gemm_bt<1><<<gg, 256, 0, stream>>>(Xb, wo, bo, d_out, D_, D_, 1.0f, 0, S_);
}

// Round 2
// 233.174 us; speedup vs baseline: 1.3267x; 1.3267x over previous
//
#include <hip/hip_runtime.h>
#include <hip/hip_bf16.h>
#include <stdint.h>

// Problem constants (B,S,D,H,M) = (2,2048,1024,16,64), HD=64, keys+mem = 2112
#define B_  2
#define S_  2048
#define D_  1024
#define H_  16
#define HD_ 64
#define M_  64
#define SKM (S_ + M_)   // 2112

typedef __attribute__((ext_vector_type(8))) short s16x8;
typedef __attribute__((ext_vector_type(4))) float f32x4;
typedef __attribute__((ext_vector_type(16))) float f32x16;

__device__ __forceinline__ unsigned short f2bf(float f) {
  union { float f; unsigned int u; } v; v.f = f;
  unsigned int r = v.u + 0x7fffu + ((v.u >> 16) & 1u);  // RNE
  return (unsigned short)(r >> 16);
}

__device__ __forceinline__ unsigned pkbf(float lo, float hi) {
  union { __hip_bfloat162 b; unsigned u; } t;
  t.b = __float22bfloat162_rn(make_float2(lo, hi));   // -> v_cvt_pk_bf16_f32
  return t.u;
}

// ---------------- f32 -> bf16 conversion (exact-grid, 4 elems/thread) ----------
__global__ void cvt_f32_to_bf16(const float* __restrict__ in,
                                unsigned short* __restrict__ out) {
  int i = (blockIdx.x * blockDim.x + threadIdx.x) * 4;
  float4 v = *(const float4*)&in[i];
  ushort4 o;
  o.x = f2bf(v.x); o.y = f2bf(v.y); o.z = f2bf(v.z); o.w = f2bf(v.w);
  *(ushort4*)&out[i] = o;
}

// ------- fill memory rows: K_mem = 8*m_k (row-major), V_mem = 8*m_v (into V^T) --
__global__ void fill_mem(const float* __restrict__ mk, const float* __restrict__ mv,
                         unsigned short* __restrict__ Kb, unsigned short* __restrict__ VtG) {
  int i = blockIdx.x * 256 + threadIdx.x;     // 0 .. M_*D_-1
  int row = i >> 10, col = i & 1023;
  int hI = col >> 6, dd = col & 63;
  unsigned short kv = f2bf(8.0f * mk[i]);
  unsigned short vv = f2bf(8.0f * mv[i]);
#pragma unroll
  for (int b = 0; b < B_; b++) {
    Kb[((size_t)(b * SKM) + S_ + row) * D_ + col] = kv;
    VtG[((size_t)(b * H_ + hI) * HD_ + dd) * SKM + S_ + row] = vv;
  }
}

// ---------------- GEMM: C = alpha*(A @ Bw^T + bias), A[M][K], Bw[N][K] bf16 ----
// 128x128 tile, BK=32, 4 waves (2x2), per-wave 64x64 = 4x4 mfma_16x16x32_bf16.
// MODE: 0 = bf16 row-major with mem-row gap, 1 = f32 row-major, 2 = bf16 V^T.
template<int MODE>
__global__ __launch_bounds__(256)
void gemm_bt(const unsigned short* __restrict__ A,
             const unsigned short* __restrict__ Bw,
             const float* __restrict__ bias,
             void* __restrict__ Cout,
             int N, int K, float alpha, int rowGap, int rowsPerBatch) {
  __shared__ __align__(16) unsigned short As[128 * 32];
  __shared__ __align__(16) unsigned short Bs[128 * 32];
  const int tid = threadIdx.x;
  const int lane = tid & 63;
  const int w = tid >> 6, wr = w >> 1, wc = w & 1;
  const int lr = lane & 15, lk = lane >> 4;
  const int mBase = blockIdx.y * 128, nBase = blockIdx.x * 128;
  const int r0 = tid >> 2, cb = tid & 3;   // staging: row, 8-elem chunk

  const f32x4 fz = {0.f, 0.f, 0.f, 0.f};
  f32x4 acc[4][4];
#pragma unroll
  for (int i = 0; i < 4; i++)
#pragma unroll
    for (int j = 0; j < 4; j++) acc[i][j] = fz;

  for (int k0 = 0; k0 < K; k0 += 32) {
    uint4 av0 = *(const uint4*)&A[(size_t)(mBase + r0) * K + k0 + cb * 8];
    uint4 av1 = *(const uint4*)&A[(size_t)(mBase + 64 + r0) * K + k0 + cb * 8];
    uint4 bv0 = *(const uint4*)&Bw[(size_t)(nBase + r0) * K + k0 + cb * 8];
    uint4 bv1 = *(const uint4*)&Bw[(size_t)(nBase + 64 + r0) * K + k0 + cb * 8];
    __syncthreads();   // previous tile's reads complete
    *(uint4*)&As[r0 * 32 + ((cb ^ (r0 & 3)) << 3)] = av0;
    *(uint4*)&As[(r0 + 64) * 32 + ((cb ^ (r0 & 3)) << 3)] = av1;
    *(uint4*)&Bs[r0 * 32 + ((cb ^ (r0 & 3)) << 3)] = bv0;
    *(uint4*)&Bs[(r0 + 64) * 32 + ((cb ^ (r0 & 3)) << 3)] = bv1;
    __syncthreads();

    s16x8 af[4], bf[4];
#pragma unroll
    for (int mi = 0; mi < 4; mi++) {
      int row = wr * 64 + mi * 16 + lr;
      af[mi] = *(const s16x8*)&As[row * 32 + ((lk ^ (row & 3)) << 3)];
    }
#pragma unroll
    for (int ni = 0; ni < 4; ni++) {
      int row = wc * 64 + ni * 16 + lr;
      bf[ni] = *(const s16x8*)&Bs[row * 32 + ((lk ^ (row & 3)) << 3)];
    }
#pragma unroll
    for (int mi = 0; mi < 4; mi++)
#pragma unroll
      for (int ni = 0; ni < 4; ni++)
        acc[mi][ni] = __builtin_amdgcn_mfma_f32_16x16x32_bf16(af[mi], bf[ni], acc[mi][ni], 0, 0, 0);
  }

  // C/D layout (m89-verified): col = lane&15, row = (lane>>4)*4 + reg
#pragma unroll
  for (int mi = 0; mi < 4; mi++)
#pragma unroll
    for (int ni = 0; ni < 4; ni++)
#pragma unroll
      for (int r = 0; r < 4; r++) {
        int gr = mBase + wr * 64 + mi * 16 + lk * 4 + r;
        int gc = nBase + wc * 64 + ni * 16 + lr;
        float v = (acc[mi][ni][r] + bias[gc]) * alpha;
        if (MODE == 1) {
          ((float*)Cout)[(size_t)gr * N + gc] = v;
        } else if (MODE == 2) {
          int bb = gr / S_, s = gr - bb * S_;
          int hI = gc >> 6, dd = gc & 63;
          ((unsigned short*)Cout)[((size_t)(bb * H_ + hI) * HD_ + dd) * SKM + s] = f2bf(v);
        } else {
          int orow = gr + (gr / rowsPerBatch) * rowGap;   // skip mem rows for K
          ((unsigned short*)Cout)[(size_t)orow * N + gc] = f2bf(v);
        }
      }
}

// -------- Flash attention, swapped-QK^T 32x32 structure (m214 family) ---------
// Block: 128 q-rows (4 waves x 32) for one (b,h). KV tile = 64 keys.
// Per lane: q = lane&31 (lanes L, L+32 duplicate q); P^T lives in registers.
__global__ __launch_bounds__(256)
void attn_kernel(const unsigned short* __restrict__ Qb,
                 const unsigned short* __restrict__ Kb,
                 const unsigned short* __restrict__ VtG,
                 const int* __restrict__ mask,
                 unsigned short* __restrict__ Xb) {
  __shared__ __align__(16) unsigned short Ks[64 * 64];   // [key][d]  swizzled
  __shared__ __align__(16) unsigned short Vs[64 * 64];   // [d][key]  swizzled
  __shared__ unsigned int mbits[2];

  const int tid = threadIdx.x, lane = tid & 63, w = tid >> 6;
  const int l31 = lane & 31, hh = lane >> 5;
  const int qt = blockIdx.x, h = blockIdx.y, b = blockIdx.z;

  const int r0 = tid >> 3, c0 = tid & 7;          // staging: row, chunk
  const int ck = c0 ^ (r0 & 7);                   // swizzled chunk ((r0+32)&7 == r0&7)
  const unsigned short* Kg = Kb + (size_t)b * SKM * D_ + (size_t)h * HD_;
  const unsigned short* Vg = VtG + (size_t)(b * H_ + h) * HD_ * SKM;

  // Q fragments (B-operand of swapped QK^T): Q[q][ds*16 + hh*8 + i]
  const unsigned short* qp = Qb + ((size_t)(b * S_) + qt * 128 + w * 32 + l31) * D_ + h * HD_;
  s16x8 qf[4];
#pragma unroll
  for (int ds = 0; ds < 4; ds++) qf[ds] = *(const s16x8*)&qp[ds * 16 + hh * 8];

  f32x16 accO[2];
#pragma unroll
  for (int dt = 0; dt < 2; dt++)
#pragma unroll
    for (int j = 0; j < 16; j++) accO[dt][j] = 0.f;
  float m_r = -1e20f, l_r = 0.f;

  uint4 kr0, kr1, vr0, vr1;
  unsigned long long mb_n = ~0ull;
  auto LOAD = [&](int kt) {
    kr0 = *(const uint4*)&Kg[(size_t)(kt * 64 + r0) * D_ + c0 * 8];
    kr1 = *(const uint4*)&Kg[(size_t)(kt * 64 + r0 + 32) * D_ + c0 * 8];
    vr0 = *(const uint4*)&Vg[(size_t)r0 * SKM + kt * 64 + c0 * 8];
    vr1 = *(const uint4*)&Vg[(size_t)(r0 + 32) * SKM + kt * 64 + c0 * 8];
    mb_n = ~0ull;
    if (w == 0) {
      int key = kt * 64 + lane;
      int mv = (key < S_) ? mask[b * S_ + key] : 1;
      mb_n = __ballot(mv != 0);
    }
  };
  LOAD(0);

  for (int kt = 0; kt < SKM / 64; ++kt) {
    __syncthreads();                 // previous tile's LDS reads complete
    *(uint4*)&Ks[r0 * 64 + ck * 8] = kr0;
    *(uint4*)&Ks[(r0 + 32) * 64 + ck * 8] = kr1;
    *(uint4*)&Vs[r0 * 64 + ck * 8] = vr0;
    *(uint4*)&Vs[(r0 + 32) * 64 + ck * 8] = vr1;
    if (tid == 0) { mbits[0] = (unsigned)mb_n; mbits[1] = (unsigned)(mb_n >> 32); }
    __syncthreads();
    if (kt + 1 < SKM / 64) LOAD(kt + 1);   // prefetch hides HBM under compute

    // ---- S^T = K · Q^T : p0 = keys 0..31, p1 = keys 32..63 (lane: q=l31) ----
    f32x16 p0, p1;
#pragma unroll
    for (int j = 0; j < 16; j++) { p0[j] = 0.f; p1[j] = 0.f; }
#pragma unroll
    for (int ds = 0; ds < 4; ds++) {
      s16x8 ka0 = *(const s16x8*)&Ks[l31 * 64 + (((ds * 2 + hh) ^ (l31 & 7)) << 3)];
      s16x8 ka1 = *(const s16x8*)&Ks[(32 + l31) * 64 + (((ds * 2 + hh) ^ (l31 & 7)) << 3)];
      p0 = __builtin_amdgcn_mfma_f32_32x32x16_bf16(ka0, qf[ds], p0, 0, 0, 0);
      p1 = __builtin_amdgcn_mfma_f32_32x32x16_bf16(ka1, qf[ds], p1, 0, 0, 0);
    }

    // ---- mask: key kl = (j&3)+8*(j>>2)+4*hh (+32 for p1); masked -> -1e30 ----
    unsigned lo = mbits[0] >> (hh * 4), hi = mbits[1] >> (hh * 4);
#pragma unroll
    for (int j = 0; j < 16; j++) {
      int bp = (j & 3) + 8 * (j >> 2);
      if (!((lo >> bp) & 1)) p0[j] = -1e30f;
      if (!((hi >> bp) & 1)) p1[j] = -1e30f;
    }

    // ---- online softmax (per-lane; pair lane L/L+32 share q) ----
    float vmax = fmaxf(p0[0], p1[0]);
#pragma unroll
    for (int j = 1; j < 16; j++) vmax = fmaxf(vmax, fmaxf(p0[j], p1[j]));
    vmax = fmaxf(vmax, __shfl_xor(vmax, 32));
    float mnew = fmaxf(m_r, vmax);
    float fac = __expf(m_r - mnew);
    m_r = mnew;
    float sum = 0.f;
#pragma unroll
    for (int j = 0; j < 16; j++) {
      p0[j] = __expf(p0[j] - mnew); sum += p0[j];
      p1[j] = __expf(p1[j] - mnew); sum += p1[j];
    }
    sum += __shfl_xor(sum, 32);
    l_r = l_r * fac + sum;
#pragma unroll
    for (int dt = 0; dt < 2; dt++)
#pragma unroll
      for (int j = 0; j < 16; j++) accO[dt][j] *= fac;

    // ---- build P^T fragments: frag[ks] = P[q][16ks + hh*8 + 0..7] as bf16x8 ----
    s16x8 pf_[4];
#pragma unroll
    for (int ks = 0; ks < 4; ks++) {
      const int base = (ks & 1) * 8;
#define ELT(t) ((ks >= 2) ? p1[base + (t)] : p0[base + (t)])
      unsigned w0 = pkbf(ELT(0), ELT(1));
      unsigned w1 = pkbf(ELT(2), ELT(3));
      unsigned w2 = pkbf(ELT(4), ELT(5));
      unsigned w3 = pkbf(ELT(6), ELT(7));
#undef ELT
      unsigned s0 = hh ? w0 : w2;         // send: h0 sends keys {8..11}, h1 sends {4..7}
      unsigned s1 = hh ? w1 : w3;
      unsigned g0 = (unsigned)__shfl_xor((int)s0, 32);
      unsigned g1 = (unsigned)__shfl_xor((int)s1, 32);
      union { s16x8 v; unsigned u[4]; } pf;
      pf.u[0] = hh ? g0 : w0;
      pf.u[1] = hh ? g1 : w1;
      pf.u[2] = hh ? w2 : g0;
      pf.u[3] = hh ? w3 : g1;
      pf_[ks] = pf.v;
    }

    // ---- O^T += V^T · P^T  (row d = dt*32+(j&3)+8*(j>>2)+4*hh, col q = l31) ----
#pragma unroll
    for (int dt = 0; dt < 2; dt++)
#pragma unroll
      for (int ks = 0; ks < 4; ks++) {
        s16x8 va = *(const s16x8*)&Vs[(dt * 32 + l31) * 64 + (((ks * 2 + hh) ^ (l31 & 7)) << 3)];
        accO[dt] = __builtin_amdgcn_mfma_f32_32x32x16_bf16(va, pf_[ks], accO[dt], 0, 0, 0);
      }
  }

  float invl = 1.0f / l_r;
  size_t orow = ((size_t)(b * S_) + qt * 128 + w * 32 + l31) * D_ + h * HD_;
#pragma unroll
  for (int dt = 0; dt < 2; dt++)
#pragma unroll
    for (int j = 0; j < 16; j++) {
      int d = dt * 32 + (j & 3) + 8 * (j >> 2) + 4 * hh;
      Xb[orow + d] = f2bf(accO[dt][j] * invl);
    }
}

// ------------------------------- launcher -------------------------------------
extern "C" void kernel_launch(void* const* d_in, const int* in_sizes, int n_in,
                              void* d_out, int out_size, void* d_ws, size_t ws_size,
                              hipStream_t stream) {
  const float* query = (const float*)d_in[0];
  const float* key   = (const float*)d_in[1];
  const float* value = (const float*)d_in[2];
  const int*   mask  = (const int*)d_in[3];
  const float* Wq    = (const float*)d_in[4];
  const float* bq    = (const float*)d_in[5];
  const float* Wk    = (const float*)d_in[6];
  const float* bk    = (const float*)d_in[7];
  const float* Wv    = (const float*)d_in[8];
  const float* bv    = (const float*)d_in[9];
  const float* Wo    = (const float*)d_in[10];
  const float* bo    = (const float*)d_in[11];
  const float* m_k   = (const float*)d_in[12];
  const float* m_v   = (const float*)d_in[13];

  const int NQ = B_ * S_ * D_;     // 4,194,304
  const int NW = D_ * D_;          // 1,048,576
  const int NK = B_ * SKM * D_;    // 4,325,376

  unsigned short* ws = (unsigned short*)d_ws;   // total use: 67.6 MB
  unsigned short* qf = ws;
  unsigned short* kf = qf + NQ;
  unsigned short* vf = kf + NQ;
  unsigned short* wq = vf + NQ;
  unsigned short* wk = wq + NW;
  unsigned short* wv = wk + NW;
  unsigned short* wo = wv + NW;
  unsigned short* Qb = wo + NW;
  unsigned short* Kb = Qb + NQ;
  unsigned short* Vt = Kb + NK;    // [b][h][d][key]
  unsigned short* Xb = Vt + NK;

  cvt_f32_to_bf16<<<NQ / 1024, 256, 0, stream>>>(query, qf);
  cvt_f32_to_bf16<<<NQ / 1024, 256, 0, stream>>>(key, kf);
  cvt_f32_to_bf16<<<NQ / 1024, 256, 0, stream>>>(value, vf);
  cvt_f32_to_bf16<<<NW / 1024, 256, 0, stream>>>(Wq, wq);
  cvt_f32_to_bf16<<<NW / 1024, 256, 0, stream>>>(Wk, wk);
  cvt_f32_to_bf16<<<NW / 1024, 256, 0, stream>>>(Wv, wv);
  cvt_f32_to_bf16<<<NW / 1024, 256, 0, stream>>>(Wo, wo);
  fill_mem<<<(M_ * D_) / 256, 256, 0, stream>>>(m_k, m_v, Kb, Vt);

  dim3 gg(D_ / 128, (B_ * S_) / 128);   // (8, 32)
  // Q scaled by 1/(sqrt(HD)=8) so attention needs no scale
  gemm_bt<0><<<gg, 256, 0, stream>>>(qf, wq, bq, Qb, D_, D_, 0.125f, 0, S_);
  gemm_bt<0><<<gg, 256, 0, stream>>>(kf, wk, bk, Kb, D_, D_, 1.0f, M_, S_);
  gemm_bt<2><<<gg, 256, 0, stream>>>(vf, wv, bv, Vt, D_, D_, 1.0f, 0, S_);

  attn_kernel<<<dim3(S_ / 128, H_, B_), 256, 0, stream>>>(Qb, Kb, Vt, mask, Xb);

  gemm_bt<1><<<gg, 256, 0, stream>>>(Xb, wo, bo, d_out, D_, D_, 1.0f, 0, S_);
}

// Round 3
// 180.344 us; speedup vs baseline: 1.7154x; 1.2929x over previous
//
#include <hip/hip_runtime.h>
#include <hip/hip_bf16.h>
#include <stdint.h>

// Problem constants (B,S,D,H,M) = (2,2048,1024,16,64), HD=64
#define B_  2
#define S_  2048
#define D_  1024
#define H_  16
#define HD_ 64
#define M_  64
#define SKM (S_ + M_)   // 2112
#define LOG2E 1.44269504088896340736f

typedef __attribute__((ext_vector_type(8))) short s16x8;
typedef __attribute__((ext_vector_type(4))) float f32x4;
typedef __attribute__((ext_vector_type(16))) float f32x16;

__device__ __forceinline__ unsigned short f2bf(float f) {
  union { float f; unsigned int u; } v; v.f = f;
  unsigned int r = v.u + 0x7fffu + ((v.u >> 16) & 1u);  // RNE
  return (unsigned short)(r >> 16);
}

__device__ __forceinline__ unsigned pkbf(float lo, float hi) {
  union { __hip_bfloat162 b; unsigned u; } t;
  t.b = __float22bfloat162_rn(make_float2(lo, hi));   // -> v_cvt_pk_bf16_f32
  return t.u;
}

// ---- mask compaction: idx[b][j] = j-th unmasked key, cnt[b] = count ----------
__global__ void compact_mask(const int* __restrict__ mask,
                             int* __restrict__ idx, int* __restrict__ cnt) {
  const int b = blockIdx.x;
  __shared__ int base, wsum[4];
  if (threadIdx.x == 0) base = 0;
  const int lane = threadIdx.x & 63, w = threadIdx.x >> 6;
  __syncthreads();
  for (int c = 0; c < S_; c += 256) {
    int key = c + threadIdx.x;
    int mv = mask[b * S_ + key];
    unsigned long long bal = __ballot(mv != 0);
    int pre = __popcll(bal & ((1ull << lane) - 1ull));
    if (lane == 0) wsum[w] = __popcll(bal);
    __syncthreads();
    int woff = 0;
    for (int i = 0; i < w; i++) woff += wsum[i];
    int tot = wsum[0] + wsum[1] + wsum[2] + wsum[3];
    if (mv) idx[b * S_ + base + woff + pre] = key;
    __syncthreads();
    if (threadIdx.x == 0) base += tot;
    __syncthreads();
  }
  if (threadIdx.x == 0) cnt[b] = base;
}

// ---------------- f32 -> bf16 conversion (exact-grid, 4 elems/thread) ----------
__global__ void cvt_f32_to_bf16(const float* __restrict__ in,
                                unsigned short* __restrict__ out) {
  int i = (blockIdx.x * blockDim.x + threadIdx.x) * 4;
  float4 v = *(const float4*)&in[i];
  ushort4 o;
  o.x = f2bf(v.x); o.y = f2bf(v.y); o.z = f2bf(v.z); o.w = f2bf(v.w);
  *(ushort4*)&out[i] = o;
}

// ---- 4 weight matrices in one launch (blockIdx.y selects) --------------------
__global__ void cvt_w4(const float* __restrict__ w0, const float* __restrict__ w1,
                       const float* __restrict__ w2, const float* __restrict__ w3,
                       unsigned short* __restrict__ o0, unsigned short* __restrict__ o1,
                       unsigned short* __restrict__ o2, unsigned short* __restrict__ o3) {
  const float* in; unsigned short* out;
  switch (blockIdx.y) {
    case 0: in = w0; out = o0; break;
    case 1: in = w1; out = o1; break;
    case 2: in = w2; out = o2; break;
    default: in = w3; out = o3; break;
  }
  int i = (blockIdx.x * 256 + threadIdx.x) * 4;
  float4 v = *(const float4*)&in[i];
  ushort4 o;
  o.x = f2bf(v.x); o.y = f2bf(v.y); o.z = f2bf(v.z); o.w = f2bf(v.w);
  *(ushort4*)&out[i] = o;
}

// ---- gather-convert key/value rows where mask=1 (one row per block) ----------
__global__ void cvt_kv_gather(const float* __restrict__ key, const float* __restrict__ value,
                              unsigned short* __restrict__ kf, unsigned short* __restrict__ vf,
                              const int* __restrict__ idx, const int* __restrict__ cnt) {
  int b = blockIdx.y, j = blockIdx.x;
  if (j >= cnt[b]) return;
  const float* in = blockIdx.z ? value : key;
  unsigned short* out = blockIdx.z ? vf : kf;
  int src = idx[b * S_ + j];
  const float* ip = in + ((size_t)(b * S_) + src) * D_;
  unsigned short* op = out + ((size_t)(b * S_) + j) * D_;
  int t = threadIdx.x * 4;
  float4 v = *(const float4*)&ip[t];
  ushort4 o;
  o.x = f2bf(v.x); o.y = f2bf(v.y); o.z = f2bf(v.z); o.w = f2bf(v.w);
  *(ushort4*)&op[t] = o;
}

// ---- memory rows appended at key position cnt[b] (AFTER the K/V GEMMs) -------
__global__ void fill_mem(const float* __restrict__ mk, const float* __restrict__ mv,
                         unsigned short* __restrict__ Kb, unsigned short* __restrict__ VtG,
                         const int* __restrict__ cnt) {
  int i = blockIdx.x * 256 + threadIdx.x;     // 0 .. M_*D_-1
  int row = i >> 10, col = i & 1023;
  int hI = col >> 6, dd = col & 63;
  unsigned short kv = f2bf(8.0f * mk[i]);
  unsigned short vv = f2bf(8.0f * mv[i]);
#pragma unroll
  for (int b = 0; b < B_; b++) {
    int c = cnt[b];
    Kb[((size_t)(b * SKM) + c + row) * D_ + col] = kv;
    VtG[((size_t)(b * H_ + hI) * HD_ + dd) * SKM + c + row] = vv;
  }
}

// ---------------- GEMM: C = alpha*(A @ Bw^T + bias), A[M][K], Bw[N][K] bf16 ----
// 128x128 tile, BK=32, 4 waves (2x2), per-wave 64x64 = 4x4 mfma_16x16x32_bf16.
// MODE: 0 = bf16 row-major with mem-row gap, 1 = f32 row-major, 2 = bf16 V^T.
// cnt != nullptr: skip blocks entirely above the per-batch compacted row count.
template<int MODE>
__global__ __launch_bounds__(256)
void gemm_bt(const unsigned short* __restrict__ A,
             const unsigned short* __restrict__ Bw,
             const float* __restrict__ bias,
             void* __restrict__ Cout,
             int N, int K, float alpha, int rowGap, int rowsPerBatch,
             const int* __restrict__ cnt) {
  __shared__ __align__(16) unsigned short As[128 * 32];
  __shared__ __align__(16) unsigned short Bs[128 * 32];
  const int mBase = blockIdx.y * 128, nBase = blockIdx.x * 128;
  if (cnt) {
    int c = (mBase < S_) ? cnt[0] : cnt[1];
    int lo = (mBase < S_) ? mBase : (mBase - S_);
    if (lo >= c) return;                        // tile fully in dead rows
  }
  const int tid = threadIdx.x;
  const int lane = tid & 63;
  const int w = tid >> 6, wr = w >> 1, wc = w & 1;
  const int lr = lane & 15, lk = lane >> 4;
  const int r0 = tid >> 2, cb = tid & 3;   // staging: row, 8-elem chunk

  const f32x4 fz = {0.f, 0.f, 0.f, 0.f};
  f32x4 acc[4][4];
#pragma unroll
  for (int i = 0; i < 4; i++)
#pragma unroll
    for (int j = 0; j < 4; j++) acc[i][j] = fz;

  for (int k0 = 0; k0 < K; k0 += 32) {
    uint4 av0 = *(const uint4*)&A[(size_t)(mBase + r0) * K + k0 + cb * 8];
    uint4 av1 = *(const uint4*)&A[(size_t)(mBase + 64 + r0) * K + k0 + cb * 8];
    uint4 bv0 = *(const uint4*)&Bw[(size_t)(nBase + r0) * K + k0 + cb * 8];
    uint4 bv1 = *(const uint4*)&Bw[(size_t)(nBase + 64 + r0) * K + k0 + cb * 8];
    __syncthreads();   // previous tile's reads complete
    *(uint4*)&As[r0 * 32 + ((cb ^ (r0 & 3)) << 3)] = av0;
    *(uint4*)&As[(r0 + 64) * 32 + ((cb ^ (r0 & 3)) << 3)] = av1;
    *(uint4*)&Bs[r0 * 32 + ((cb ^ (r0 & 3)) << 3)] = bv0;
    *(uint4*)&Bs[(r0 + 64) * 32 + ((cb ^ (r0 & 3)) << 3)] = bv1;
    __syncthreads();

    s16x8 af[4], bf[4];
#pragma unroll
    for (int mi = 0; mi < 4; mi++) {
      int row = wr * 64 + mi * 16 + lr;
      af[mi] = *(const s16x8*)&As[row * 32 + ((lk ^ (row & 3)) << 3)];
    }
#pragma unroll
    for (int ni = 0; ni < 4; ni++) {
      int row = wc * 64 + ni * 16 + lr;
      bf[ni] = *(const s16x8*)&Bs[row * 32 + ((lk ^ (row & 3)) << 3)];
    }
#pragma unroll
    for (int mi = 0; mi < 4; mi++)
#pragma unroll
      for (int ni = 0; ni < 4; ni++)
        acc[mi][ni] = __builtin_amdgcn_mfma_f32_16x16x32_bf16(af[mi], bf[ni], acc[mi][ni], 0, 0, 0);
  }

  // C/D layout (m89-verified): col = lane&15, row = (lane>>4)*4 + reg
#pragma unroll
  for (int mi = 0; mi < 4; mi++)
#pragma unroll
    for (int ni = 0; ni < 4; ni++)
#pragma unroll
      for (int r = 0; r < 4; r++) {
        int gr = mBase + wr * 64 + mi * 16 + lk * 4 + r;
        int gc = nBase + wc * 64 + ni * 16 + lr;
        float v = (acc[mi][ni][r] + bias[gc]) * alpha;
        if (MODE == 1) {
          ((float*)Cout)[(size_t)gr * N + gc] = v;
        } else if (MODE == 2) {
          int bb = gr / S_, s = gr - bb * S_;
          int hI = gc >> 6, dd = gc & 63;
          ((unsigned short*)Cout)[((size_t)(bb * H_ + hI) * HD_ + dd) * SKM + s] = f2bf(v);
        } else {
          int orow = gr + (gr / rowsPerBatch) * rowGap;   // batch gap for K rows
          ((unsigned short*)Cout)[(size_t)orow * N + gc] = f2bf(v);
        }
      }
}

// -------- Flash attention over compacted keys + memory slots ------------------
// Block: 128 q-rows (4 waves x 32) for one (b,h). KV tile = 64 keys.
// Per lane: q = lane&31; P^T in registers; scores are in log2 units (LOG2E
// folded into Q projection) so softmax uses v_exp_f32 directly.
__global__ __launch_bounds__(256)
void attn_kernel(const unsigned short* __restrict__ Qb,
                 const unsigned short* __restrict__ Kb,
                 const unsigned short* __restrict__ VtG,
                 const int* __restrict__ cnt,
                 unsigned short* __restrict__ Xb) {
  __shared__ __align__(16) unsigned short Ks[64 * 64];   // [key][d]  swizzled
  __shared__ __align__(16) unsigned short Vs[64 * 64];   // [d][key]  swizzled

  const int tid = threadIdx.x, lane = tid & 63, w = tid >> 6;
  const int l31 = lane & 31, hh = lane >> 5;
  const int qt = blockIdx.x, h = blockIdx.y, b = blockIdx.z;

  const int total = cnt[b] + M_;            // live keys incl. memory slots
  const int nt = (total + 63) >> 6;         // tiles (<= 33)

  const int r0 = tid >> 3, c0 = tid & 7;          // staging: row, chunk
  const int ck = c0 ^ (r0 & 7);                   // swizzled ((r0+32)&7 == r0&7)
  const unsigned short* Kg = Kb + (size_t)b * SKM * D_ + (size_t)h * HD_;
  const unsigned short* Vg = VtG + (size_t)(b * H_ + h) * HD_ * SKM;

  // Q fragments (B-operand of swapped QK^T): Q[q][ds*16 + hh*8 + i]
  const unsigned short* qp = Qb + ((size_t)(b * S_) + qt * 128 + w * 32 + l31) * D_ + h * HD_;
  s16x8 qf[4];
#pragma unroll
  for (int ds = 0; ds < 4; ds++) qf[ds] = *(const s16x8*)&qp[ds * 16 + hh * 8];

  f32x16 accO[2];
#pragma unroll
  for (int dt = 0; dt < 2; dt++)
#pragma unroll
    for (int j = 0; j < 16; j++) accO[dt][j] = 0.f;
  float m_r = -1e20f, l_r = 0.f;

  uint4 kr0, kr1, vr0, vr1;
  auto LOAD = [&](int kt) {   // rows < nt*64 <= 2112, always in-bounds
    kr0 = *(const uint4*)&Kg[(size_t)(kt * 64 + r0) * D_ + c0 * 8];
    kr1 = *(const uint4*)&Kg[(size_t)(kt * 64 + r0 + 32) * D_ + c0 * 8];
    vr0 = *(const uint4*)&Vg[(size_t)r0 * SKM + kt * 64 + c0 * 8];
    vr1 = *(const uint4*)&Vg[(size_t)(r0 + 32) * SKM + kt * 64 + c0 * 8];
  };
  LOAD(0);

  for (int kt = 0; kt < nt; ++kt) {
    __syncthreads();                 // previous tile's LDS reads complete
    *(uint4*)&Ks[r0 * 64 + ck * 8] = kr0;
    *(uint4*)&Ks[(r0 + 32) * 64 + ck * 8] = kr1;
    *(uint4*)&Vs[r0 * 64 + ck * 8] = vr0;
    *(uint4*)&Vs[(r0 + 32) * 64 + ck * 8] = vr1;
    __syncthreads();
    if (kt + 1 < nt) LOAD(kt + 1);   // prefetch hides HBM under compute

    // ---- S^T = K · Q^T : p0 = keys 0..31, p1 = keys 32..63 (lane: q=l31) ----
    f32x16 p0, p1;
#pragma unroll
    for (int j = 0; j < 16; j++) { p0[j] = 0.f; p1[j] = 0.f; }
#pragma unroll
    for (int ds = 0; ds < 4; ds++) {
      s16x8 ka0 = *(const s16x8*)&Ks[l31 * 64 + (((ds * 2 + hh) ^ (l31 & 7)) << 3)];
      s16x8 ka1 = *(const s16x8*)&Ks[(32 + l31) * 64 + (((ds * 2 + hh) ^ (l31 & 7)) << 3)];
      p0 = __builtin_amdgcn_mfma_f32_32x32x16_bf16(ka0, qf[ds], p0, 0, 0, 0);
      p1 = __builtin_amdgcn_mfma_f32_32x32x16_bf16(ka1, qf[ds], p1, 0, 0, 0);
    }

    // ---- tail tile: kill keys beyond `total` (key = (j&3)+8*(j>>2)+4*hh) ----
    if (kt == nt - 1) {
      int valid = total - kt * 64;   // 1..64
#pragma unroll
      for (int j = 0; j < 16; j++) {
        int kl = (j & 3) + 8 * (j >> 2) + 4 * hh;
        if (kl >= valid) p0[j] = -1e30f;
        if (kl + 32 >= valid) p1[j] = -1e30f;
      }
    }

    // ---- online softmax in log2 units, defer-max (T13, THR=8) ----
    float vmax = fmaxf(p0[0], p1[0]);
#pragma unroll
    for (int j = 1; j < 16; j++) vmax = fmaxf(vmax, fmaxf(p0[j], p1[j]));
    vmax = fmaxf(vmax, __shfl_xor(vmax, 32));
    if (!__all(vmax - m_r <= 8.0f)) {
      float mnew = fmaxf(m_r, vmax);
      float fac = __builtin_amdgcn_exp2f(m_r - mnew);
      m_r = mnew;
      l_r *= fac;
#pragma unroll
      for (int dt = 0; dt < 2; dt++)
#pragma unroll
        for (int j = 0; j < 16; j++) accO[dt][j] *= fac;
    }
    float sum = 0.f;
#pragma unroll
    for (int j = 0; j < 16; j++) {
      p0[j] = __builtin_amdgcn_exp2f(p0[j] - m_r); sum += p0[j];
      p1[j] = __builtin_amdgcn_exp2f(p1[j] - m_r); sum += p1[j];
    }
    sum += __shfl_xor(sum, 32);
    l_r += sum;

    // ---- build P^T fragments: frag[ks] = P[q][16ks + hh*8 + 0..7] as bf16x8 ----
    s16x8 pf_[4];
#pragma unroll
    for (int ks = 0; ks < 4; ks++) {
      const int base = (ks & 1) * 8;
#define ELT(t) ((ks >= 2) ? p1[base + (t)] : p0[base + (t)])
      unsigned w0 = pkbf(ELT(0), ELT(1));
      unsigned w1 = pkbf(ELT(2), ELT(3));
      unsigned w2 = pkbf(ELT(4), ELT(5));
      unsigned w3 = pkbf(ELT(6), ELT(7));
#undef ELT
      unsigned s0 = hh ? w0 : w2;         // h0 sends keys {8..11}, h1 sends {4..7}
      unsigned s1 = hh ? w1 : w3;
      unsigned g0 = (unsigned)__shfl_xor((int)s0, 32);
      unsigned g1 = (unsigned)__shfl_xor((int)s1, 32);
      union { s16x8 v; unsigned u[4]; } pf;
      pf.u[0] = hh ? g0 : w0;
      pf.u[1] = hh ? g1 : w1;
      pf.u[2] = hh ? w2 : g0;
      pf.u[3] = hh ? w3 : g1;
      pf_[ks] = pf.v;
    }

    // ---- O^T += V^T · P^T  (row d = dt*32+(j&3)+8*(j>>2)+4*hh, col q = l31) ----
#pragma unroll
    for (int dt = 0; dt < 2; dt++)
#pragma unroll
      for (int ks = 0; ks < 4; ks++) {
        s16x8 va = *(const s16x8*)&Vs[(dt * 32 + l31) * 64 + (((ks * 2 + hh) ^ (l31 & 7)) << 3)];
        accO[dt] = __builtin_amdgcn_mfma_f32_32x32x16_bf16(va, pf_[ks], accO[dt], 0, 0, 0);
      }
  }

  float invl = 1.0f / l_r;
  size_t orow = ((size_t)(b * S_) + qt * 128 + w * 32 + l31) * D_ + h * HD_;
#pragma unroll
  for (int dt = 0; dt < 2; dt++)
#pragma unroll
    for (int j = 0; j < 16; j++) {
      int d = dt * 32 + (j & 3) + 8 * (j >> 2) + 4 * hh;
      Xb[orow + d] = f2bf(accO[dt][j] * invl);
    }
}

// ------------------------------- launcher -------------------------------------
extern "C" void kernel_launch(void* const* d_in, const int* in_sizes, int n_in,
                              void* d_out, int out_size, void* d_ws, size_t ws_size,
                              hipStream_t stream) {
  const float* query = (const float*)d_in[0];
  const float* key   = (const float*)d_in[1];
  const float* value = (const float*)d_in[2];
  const int*   mask  = (const int*)d_in[3];
  const float* Wq    = (const float*)d_in[4];
  const float* bq    = (const float*)d_in[5];
  const float* Wk    = (const float*)d_in[6];
  const float* bk    = (const float*)d_in[7];
  const float* Wv    = (const float*)d_in[8];
  const float* bv    = (const float*)d_in[9];
  const float* Wo    = (const float*)d_in[10];
  const float* bo    = (const float*)d_in[11];
  const float* m_k   = (const float*)d_in[12];
  const float* m_v   = (const float*)d_in[13];

  const int NQ = B_ * S_ * D_;     // 4,194,304
  const int NW = D_ * D_;          // 1,048,576
  const int NK = B_ * SKM * D_;    // 4,325,376

  unsigned short* ws = (unsigned short*)d_ws;   // ~67.6 MB + 16 KB
  unsigned short* qf = ws;
  unsigned short* kf = qf + NQ;
  unsigned short* vf = kf + NQ;
  unsigned short* wq = vf + NQ;
  unsigned short* wk = wq + NW;
  unsigned short* wv = wk + NW;
  unsigned short* wo = wv + NW;
  unsigned short* Qb = wo + NW;
  unsigned short* Kb = Qb + NQ;
  unsigned short* Vt = Kb + NK;    // [b][h][d][key]
  unsigned short* Xb = Vt + NK;
  int* idx = (int*)(Xb + NQ);      // [B][S]
  int* cnt = idx + B_ * S_;        // [B]

  compact_mask<<<B_, 256, 0, stream>>>(mask, idx, cnt);
  cvt_f32_to_bf16<<<NQ / 1024, 256, 0, stream>>>(query, qf);
  cvt_kv_gather<<<dim3(S_, B_, 2), 256, 0, stream>>>(key, value, kf, vf, idx, cnt);
  cvt_w4<<<dim3(NW / 1024, 4), 256, 0, stream>>>(Wq, Wk, Wv, Wo, wq, wk, wv, wo);

  dim3 gg(D_ / 128, (B_ * S_) / 128);   // (8, 32)
  // Q scale: 1/sqrt(HD)=1/8 and LOG2E folded in (softmax runs in log2 units)
  gemm_bt<0><<<gg, 256, 0, stream>>>(qf, wq, bq, Qb, D_, D_, 0.125f * LOG2E, 0, S_, nullptr);
  gemm_bt<0><<<gg, 256, 0, stream>>>(kf, wk, bk, Kb, D_, D_, 1.0f, M_, S_, cnt);
  gemm_bt<2><<<gg, 256, 0, stream>>>(vf, wv, bv, Vt, D_, D_, 1.0f, 0, S_, cnt);
  // memory rows appended at key position cnt[b] — must run AFTER K/V GEMMs
  // (straddling GEMM tiles write garbage into rows >= cnt)
  fill_mem<<<(M_ * D_) / 256, 256, 0, stream>>>(m_k, m_v, Kb, Vt, cnt);

  attn_kernel<<<dim3(S_ / 128, H_, B_), 256, 0, stream>>>(Qb, Kb, Vt, cnt, Xb);

  gemm_bt<1><<<gg, 256, 0, stream>>>(Xb, wo, bo, d_out, D_, D_, 1.0f, 0, S_, nullptr);
}

// Round 4
// 146.705 us; speedup vs baseline: 2.1087x; 1.2293x over previous
//
#include <hip/hip_runtime.h>
#include <hip/hip_bf16.h>
#include <stdint.h>

// Problem constants (B,S,D,H,M) = (2,2048,1024,16,64), HD=64
#define B_  2
#define S_  2048
#define D_  1024
#define H_  16
#define HD_ 64
#define M_  64
#define SKM (S_ + M_)   // 2112
#define LOG2E 1.44269504088896340736f

typedef __attribute__((ext_vector_type(8))) short s16x8;
typedef __attribute__((ext_vector_type(4))) float f32x4;
typedef __attribute__((ext_vector_type(16))) float f32x16;

// global_load_lds width=16: linear LDS dest (base + lane*16), per-lane global src
#define GLOAD16(gp, lp) __builtin_amdgcn_global_load_lds( \
    (const __attribute__((address_space(1))) void*)(gp),  \
    (__attribute__((address_space(3))) void*)(lp), 16, 0, 0)

__device__ __forceinline__ unsigned short f2bf(float f) {
  union { float f; unsigned int u; } v; v.f = f;
  unsigned int r = v.u + 0x7fffu + ((v.u >> 16) & 1u);  // RNE
  return (unsigned short)(r >> 16);
}

__device__ __forceinline__ unsigned pkbf(float lo, float hi) {
  union { __hip_bfloat162 b; unsigned u; } t;
  t.b = __float22bfloat162_rn(make_float2(lo, hi));   // -> v_cvt_pk_bf16_f32
  return t.u;
}

// ---- mask compaction: idx[b][j] = j-th unmasked key, cnt[b] = count ----------
__global__ void compact_mask(const int* __restrict__ mask,
                             int* __restrict__ idx, int* __restrict__ cnt) {
  const int b = blockIdx.x;
  __shared__ int base, wsum[4];
  if (threadIdx.x == 0) base = 0;
  const int lane = threadIdx.x & 63, w = threadIdx.x >> 6;
  __syncthreads();
  for (int c = 0; c < S_; c += 256) {
    int key = c + threadIdx.x;
    int mv = mask[b * S_ + key];
    unsigned long long bal = __ballot(mv != 0);
    int pre = __popcll(bal & ((1ull << lane) - 1ull));
    if (lane == 0) wsum[w] = __popcll(bal);
    __syncthreads();
    int woff = 0;
    for (int i = 0; i < w; i++) woff += wsum[i];
    int tot = wsum[0] + wsum[1] + wsum[2] + wsum[3];
    if (mv) idx[b * S_ + base + woff + pre] = key;
    __syncthreads();
    if (threadIdx.x == 0) base += tot;
    __syncthreads();
  }
  if (threadIdx.x == 0) cnt[b] = base;
}

// ---------------- f32 -> bf16 conversion (exact-grid, 4 elems/thread) ----------
__global__ void cvt_f32_to_bf16(const float* __restrict__ in,
                                unsigned short* __restrict__ out) {
  int i = (blockIdx.x * blockDim.x + threadIdx.x) * 4;
  float4 v = *(const float4*)&in[i];
  ushort4 o;
  o.x = f2bf(v.x); o.y = f2bf(v.y); o.z = f2bf(v.z); o.w = f2bf(v.w);
  *(ushort4*)&out[i] = o;
}

// ---- 4 weight matrices in one launch (blockIdx.y selects) --------------------
__global__ void cvt_w4(const float* __restrict__ w0, const float* __restrict__ w1,
                       const float* __restrict__ w2, const float* __restrict__ w3,
                       unsigned short* __restrict__ o0, unsigned short* __restrict__ o1,
                       unsigned short* __restrict__ o2, unsigned short* __restrict__ o3) {
  const float* in; unsigned short* out;
  switch (blockIdx.y) {
    case 0: in = w0; out = o0; break;
    case 1: in = w1; out = o1; break;
    case 2: in = w2; out = o2; break;
    default: in = w3; out = o3; break;
  }
  int i = (blockIdx.x * 256 + threadIdx.x) * 4;
  float4 v = *(const float4*)&in[i];
  ushort4 o;
  o.x = f2bf(v.x); o.y = f2bf(v.y); o.z = f2bf(v.z); o.w = f2bf(v.w);
  *(ushort4*)&out[i] = o;
}

// ---- gather-convert key/value rows where mask=1 (one row per block) ----------
__global__ void cvt_kv_gather(const float* __restrict__ key, const float* __restrict__ value,
                              unsigned short* __restrict__ kf, unsigned short* __restrict__ vf,
                              const int* __restrict__ idx, const int* __restrict__ cnt) {
  int b = blockIdx.y, j = blockIdx.x;
  if (j >= cnt[b]) return;
  const float* in = blockIdx.z ? value : key;
  unsigned short* out = blockIdx.z ? vf : kf;
  int src = idx[b * S_ + j];
  const float* ip = in + ((size_t)(b * S_) + src) * D_;
  unsigned short* op = out + ((size_t)(b * S_) + j) * D_;
  int t = threadIdx.x * 4;
  float4 v = *(const float4*)&ip[t];
  ushort4 o;
  o.x = f2bf(v.x); o.y = f2bf(v.y); o.z = f2bf(v.z); o.w = f2bf(v.w);
  *(ushort4*)&op[t] = o;
}

// ---- memory rows appended at key position cnt[b] (AFTER the K/V GEMMs) -------
__global__ void fill_mem(const float* __restrict__ mk, const float* __restrict__ mv,
                         unsigned short* __restrict__ Kb, unsigned short* __restrict__ VtG,
                         const int* __restrict__ cnt) {
  int i = blockIdx.x * 256 + threadIdx.x;     // 0 .. M_*D_-1
  int row = i >> 10, col = i & 1023;
  int hI = col >> 6, dd = col & 63;
  unsigned short kv = f2bf(8.0f * mk[i]);
  unsigned short vv = f2bf(8.0f * mv[i]);
#pragma unroll
  for (int b = 0; b < B_; b++) {
    int c = cnt[b];
    Kb[((size_t)(b * SKM) + c + row) * D_ + col] = kv;
    VtG[((size_t)(b * H_ + hI) * HD_ + dd) * SKM + c + row] = vv;
  }
}

// ---------------- GEMM core: 128x128 tile, BK=64, global_load_lds staging -----
// LDS [128][64] bf16, chunk-XOR swizzle c^(row&7) applied via pre-swizzled
// global source (linear DMA dest) + swizzled ds_read (rule #21 both-sides).
__device__ __forceinline__ void gemm_core(
    const unsigned short* __restrict__ A,
    const unsigned short* __restrict__ Bw,
    unsigned short* As, unsigned short* Bs,
    int mBase, int nBase, int K,
    int w, int lane, int wr, int wc, int lr, int lk,
    f32x4 acc[4][4]) {
  const int sr = lane >> 3, sc = lane & 7;   // staging row-within-8, chunk slot
  for (int k0 = 0; k0 < K; k0 += 64) {
    __syncthreads();   // all waves done reading previous K-step's LDS
#pragma unroll
    for (int i = 0; i < 4; i++) {
      int r = w * 32 + i * 8 + sr;
      int c = sc ^ (r & 7);                  // inverse-swizzled source chunk
      GLOAD16(&A[(size_t)(mBase + r) * K + k0 + c * 8], &As[(w * 32 + i * 8) * 64]);
      GLOAD16(&Bw[(size_t)(nBase + r) * K + k0 + c * 8], &Bs[(w * 32 + i * 8) * 64]);
    }
    __syncthreads();   // drains vmcnt(0): DMA'd tile visible
#pragma unroll
    for (int ks = 0; ks < 2; ks++) {
      s16x8 af[4], bf[4];
#pragma unroll
      for (int mi = 0; mi < 4; mi++) {
        int row = wr * 64 + mi * 16 + lr;
        af[mi] = *(const s16x8*)&As[row * 64 + (((ks * 4 + lk) ^ (row & 7)) << 3)];
      }
#pragma unroll
      for (int ni = 0; ni < 4; ni++) {
        int row = wc * 64 + ni * 16 + lr;
        bf[ni] = *(const s16x8*)&Bs[row * 64 + (((ks * 4 + lk) ^ (row & 7)) << 3)];
      }
#pragma unroll
      for (int mi = 0; mi < 4; mi++)
#pragma unroll
        for (int ni = 0; ni < 4; ni++)
          acc[mi][ni] = __builtin_amdgcn_mfma_f32_16x16x32_bf16(af[mi], bf[ni], acc[mi][ni], 0, 0, 0);
    }
  }
}

// ---- merged Q/K/V projection: blockIdx.z selects {Q, K, V^T} -----------------
__global__ __launch_bounds__(256)
void gemm_qkv(const unsigned short* __restrict__ qf, const unsigned short* __restrict__ kf,
              const unsigned short* __restrict__ vf,
              const unsigned short* __restrict__ wq, const unsigned short* __restrict__ wk,
              const unsigned short* __restrict__ wv,
              const float* __restrict__ bq, const float* __restrict__ bk,
              const float* __restrict__ bv,
              unsigned short* __restrict__ Qb, unsigned short* __restrict__ Kb,
              unsigned short* __restrict__ Vt,
              const int* __restrict__ cnt) {
  __shared__ __align__(16) unsigned short As[128 * 64];
  __shared__ __align__(16) unsigned short Bs[128 * 64];
  const int z = blockIdx.z;
  const int mBase = blockIdx.y * 128, nBase = blockIdx.x * 128;
  if (z) {   // K/V: skip tiles entirely beyond the compacted row count
    int c = (mBase < S_) ? cnt[0] : cnt[1];
    int lo = (mBase < S_) ? mBase : (mBase - S_);
    if (lo >= c) return;
  }
  const unsigned short* A  = (z == 0) ? qf : (z == 1) ? kf : vf;
  const unsigned short* Bw = (z == 0) ? wq : (z == 1) ? wk : wv;
  const float* bias        = (z == 0) ? bq : (z == 1) ? bk : bv;

  const int tid = threadIdx.x, lane = tid & 63;
  const int w = tid >> 6, wr = w >> 1, wc = w & 1;
  const int lr = lane & 15, lk = lane >> 4;

  const f32x4 fz = {0.f, 0.f, 0.f, 0.f};
  f32x4 acc[4][4];
#pragma unroll
  for (int i = 0; i < 4; i++)
#pragma unroll
    for (int j = 0; j < 4; j++) acc[i][j] = fz;

  gemm_core(A, Bw, As, Bs, mBase, nBase, D_, w, lane, wr, wc, lr, lk, acc);

  const float alpha = (z == 0) ? 0.125f * LOG2E : 1.0f;   // Q: 1/sqrt(HD) * log2(e)
#pragma unroll
  for (int mi = 0; mi < 4; mi++)
#pragma unroll
    for (int ni = 0; ni < 4; ni++)
#pragma unroll
      for (int r = 0; r < 4; r++) {
        int gr = mBase + wr * 64 + mi * 16 + lk * 4 + r;
        int gc = nBase + wc * 64 + ni * 16 + lr;
        float v = (acc[mi][ni][r] + bias[gc]) * alpha;
        if (z == 2) {        // V^T: [b][h][d][key]
          int bb = gr / S_, s = gr - bb * S_;
          int hI = gc >> 6, dd = gc & 63;
          Vt[((size_t)(bb * H_ + hI) * HD_ + dd) * SKM + s] = f2bf(v);
        } else if (z == 1) { // K rows with per-batch mem-row gap
          int orow = gr + (gr / S_) * M_;
          Kb[(size_t)orow * D_ + gc] = f2bf(v);
        } else {
          Qb[(size_t)gr * D_ + gc] = f2bf(v);
        }
      }
}

// ---- output projection: f32 out --------------------------------------------
__global__ __launch_bounds__(256)
void gemm_o(const unsigned short* __restrict__ A, const unsigned short* __restrict__ Bw,
            const float* __restrict__ bias, float* __restrict__ Cout) {
  __shared__ __align__(16) unsigned short As[128 * 64];
  __shared__ __align__(16) unsigned short Bs[128 * 64];
  const int mBase = blockIdx.y * 128, nBase = blockIdx.x * 128;
  const int tid = threadIdx.x, lane = tid & 63;
  const int w = tid >> 6, wr = w >> 1, wc = w & 1;
  const int lr = lane & 15, lk = lane >> 4;

  const f32x4 fz = {0.f, 0.f, 0.f, 0.f};
  f32x4 acc[4][4];
#pragma unroll
  for (int i = 0; i < 4; i++)
#pragma unroll
    for (int j = 0; j < 4; j++) acc[i][j] = fz;

  gemm_core(A, Bw, As, Bs, mBase, nBase, D_, w, lane, wr, wc, lr, lk, acc);

#pragma unroll
  for (int mi = 0; mi < 4; mi++)
#pragma unroll
    for (int ni = 0; ni < 4; ni++)
#pragma unroll
      for (int r = 0; r < 4; r++) {
        int gr = mBase + wr * 64 + mi * 16 + lk * 4 + r;
        int gc = nBase + wc * 64 + ni * 16 + lr;
        Cout[(size_t)gr * D_ + gc] = acc[mi][ni][r] + bias[gc];
      }
}

// -------- Flash attention over compacted keys + memory slots ------------------
// Block: 128 q-rows (4 waves x 32) for one (b,h). KV tile = 64 keys.
// Per lane: q = lane&31; P^T in registers; scores in log2 units (LOG2E in Q).
__global__ __launch_bounds__(256)
void attn_kernel(const unsigned short* __restrict__ Qb,
                 const unsigned short* __restrict__ Kb,
                 const unsigned short* __restrict__ VtG,
                 const int* __restrict__ cnt,
                 unsigned short* __restrict__ Xb) {
  __shared__ __align__(16) unsigned short Ks[64 * 64];   // [key][d]  swizzled
  __shared__ __align__(16) unsigned short Vs[64 * 64];   // [d][key]  swizzled

  const int tid = threadIdx.x, lane = tid & 63, w = tid >> 6;
  const int l31 = lane & 31, hh = lane >> 5;
  const int qt = blockIdx.x, h = blockIdx.y, b = blockIdx.z;

  const int total = cnt[b] + M_;            // live keys incl. memory slots
  const int nt = (total + 63) >> 6;         // tiles (<= 33)

  const int r0 = tid >> 3, c0 = tid & 7;          // staging: row, chunk
  const int ck = c0 ^ (r0 & 7);                   // swizzled ((r0+32)&7 == r0&7)
  const unsigned short* Kg = Kb + (size_t)b * SKM * D_ + (size_t)h * HD_;
  const unsigned short* Vg = VtG + (size_t)(b * H_ + h) * HD_ * SKM;

  // Q fragments (B-operand of swapped QK^T): Q[q][ds*16 + hh*8 + i]
  const unsigned short* qp = Qb + ((size_t)(b * S_) + qt * 128 + w * 32 + l31) * D_ + h * HD_;
  s16x8 qf[4];
#pragma unroll
  for (int ds = 0; ds < 4; ds++) qf[ds] = *(const s16x8*)&qp[ds * 16 + hh * 8];

  f32x16 accO[2];
#pragma unroll
  for (int dt = 0; dt < 2; dt++)
#pragma unroll
    for (int j = 0; j < 16; j++) accO[dt][j] = 0.f;
  float m_r = -1e20f, l_r = 0.f;

  uint4 kr0, kr1, vr0, vr1;
  auto LOAD = [&](int kt) {   // rows < nt*64 <= 2112, always in-bounds
    kr0 = *(const uint4*)&Kg[(size_t)(kt * 64 + r0) * D_ + c0 * 8];
    kr1 = *(const uint4*)&Kg[(size_t)(kt * 64 + r0 + 32) * D_ + c0 * 8];
    vr0 = *(const uint4*)&Vg[(size_t)r0 * SKM + kt * 64 + c0 * 8];
    vr1 = *(const uint4*)&Vg[(size_t)(r0 + 32) * SKM + kt * 64 + c0 * 8];
  };
  LOAD(0);

  for (int kt = 0; kt < nt; ++kt) {
    __syncthreads();                 // previous tile's LDS reads complete
    *(uint4*)&Ks[r0 * 64 + ck * 8] = kr0;
    *(uint4*)&Ks[(r0 + 32) * 64 + ck * 8] = kr1;
    *(uint4*)&Vs[r0 * 64 + ck * 8] = vr0;
    *(uint4*)&Vs[(r0 + 32) * 64 + ck * 8] = vr1;
    __syncthreads();
    if (kt + 1 < nt) LOAD(kt + 1);   // prefetch hides HBM under compute

    // ---- S^T = K · Q^T : p0 = keys 0..31, p1 = keys 32..63 (lane: q=l31) ----
    f32x16 p0, p1;
#pragma unroll
    for (int j = 0; j < 16; j++) { p0[j] = 0.f; p1[j] = 0.f; }
#pragma unroll
    for (int ds = 0; ds < 4; ds++) {
      s16x8 ka0 = *(const s16x8*)&Ks[l31 * 64 + (((ds * 2 + hh) ^ (l31 & 7)) << 3)];
      s16x8 ka1 = *(const s16x8*)&Ks[(32 + l31) * 64 + (((ds * 2 + hh) ^ (l31 & 7)) << 3)];
      p0 = __builtin_amdgcn_mfma_f32_32x32x16_bf16(ka0, qf[ds], p0, 0, 0, 0);
      p1 = __builtin_amdgcn_mfma_f32_32x32x16_bf16(ka1, qf[ds], p1, 0, 0, 0);
    }

    // ---- tail tile: kill keys beyond `total` (key = (j&3)+8*(j>>2)+4*hh) ----
    if (kt == nt - 1) {
      int valid = total - kt * 64;   // 1..64
#pragma unroll
      for (int j = 0; j < 16; j++) {
        int kl = (j & 3) + 8 * (j >> 2) + 4 * hh;
        if (kl >= valid) p0[j] = -1e30f;
        if (kl + 32 >= valid) p1[j] = -1e30f;
      }
    }

    // ---- online softmax in log2 units, defer-max (T13, THR=8) ----
    float vmax = fmaxf(p0[0], p1[0]);
#pragma unroll
    for (int j = 1; j < 16; j++) vmax = fmaxf(vmax, fmaxf(p0[j], p1[j]));
    vmax = fmaxf(vmax, __shfl_xor(vmax, 32));
    if (!__all(vmax - m_r <= 8.0f)) {
      float mnew = fmaxf(m_r, vmax);
      float fac = __builtin_amdgcn_exp2f(m_r - mnew);
      m_r = mnew;
      l_r *= fac;
#pragma unroll
      for (int dt = 0; dt < 2; dt++)
#pragma unroll
        for (int j = 0; j < 16; j++) accO[dt][j] *= fac;
    }
    float sum = 0.f;
#pragma unroll
    for (int j = 0; j < 16; j++) {
      p0[j] = __builtin_amdgcn_exp2f(p0[j] - m_r); sum += p0[j];
      p1[j] = __builtin_amdgcn_exp2f(p1[j] - m_r); sum += p1[j];
    }
    sum += __shfl_xor(sum, 32);
    l_r += sum;

    // ---- build P^T fragments: frag[ks] = P[q][16ks + hh*8 + 0..7] as bf16x8 ----
    s16x8 pf_[4];
#pragma unroll
    for (int ks = 0; ks < 4; ks++) {
      const int base = (ks & 1) * 8;
#define ELT(t) ((ks >= 2) ? p1[base + (t)] : p0[base + (t)])
      unsigned w0 = pkbf(ELT(0), ELT(1));
      unsigned w1 = pkbf(ELT(2), ELT(3));
      unsigned w2 = pkbf(ELT(4), ELT(5));
      unsigned w3 = pkbf(ELT(6), ELT(7));
#undef ELT
      unsigned s0 = hh ? w0 : w2;         // h0 sends keys {8..11}, h1 sends {4..7}
      unsigned s1 = hh ? w1 : w3;
      unsigned g0 = (unsigned)__shfl_xor((int)s0, 32);
      unsigned g1 = (unsigned)__shfl_xor((int)s1, 32);
      union { s16x8 v; unsigned u[4]; } pf;
      pf.u[0] = hh ? g0 : w0;
      pf.u[1] = hh ? g1 : w1;
      pf.u[2] = hh ? w2 : g0;
      pf.u[3] = hh ? w3 : g1;
      pf_[ks] = pf.v;
    }

    // ---- O^T += V^T · P^T  (row d = dt*32+(j&3)+8*(j>>2)+4*hh, col q = l31) ----
#pragma unroll
    for (int dt = 0; dt < 2; dt++)
#pragma unroll
      for (int ks = 0; ks < 4; ks++) {
        s16x8 va = *(const s16x8*)&Vs[(dt * 32 + l31) * 64 + (((ks * 2 + hh) ^ (l31 & 7)) << 3)];
        accO[dt] = __builtin_amdgcn_mfma_f32_32x32x16_bf16(va, pf_[ks], accO[dt], 0, 0, 0);
      }
  }

  float invl = 1.0f / l_r;
  size_t orow = ((size_t)(b * S_) + qt * 128 + w * 32 + l31) * D_ + h * HD_;
#pragma unroll
  for (int dt = 0; dt < 2; dt++)
#pragma unroll
    for (int j = 0; j < 16; j++) {
      int d = dt * 32 + (j & 3) + 8 * (j >> 2) + 4 * hh;
      Xb[orow + d] = f2bf(accO[dt][j] * invl);
    }
}

// ------------------------------- launcher -------------------------------------
extern "C" void kernel_launch(void* const* d_in, const int* in_sizes, int n_in,
                              void* d_out, int out_size, void* d_ws, size_t ws_size,
                              hipStream_t stream) {
  const float* query = (const float*)d_in[0];
  const float* key   = (const float*)d_in[1];
  const float* value = (const float*)d_in[2];
  const int*   mask  = (const int*)d_in[3];
  const float* Wq    = (const float*)d_in[4];
  const float* bq    = (const float*)d_in[5];
  const float* Wk    = (const float*)d_in[6];
  const float* bk    = (const float*)d_in[7];
  const float* Wv    = (const float*)d_in[8];
  const float* bv    = (const float*)d_in[9];
  const float* Wo    = (const float*)d_in[10];
  const float* bo    = (const float*)d_in[11];
  const float* m_k   = (const float*)d_in[12];
  const float* m_v   = (const float*)d_in[13];

  const int NQ = B_ * S_ * D_;     // 4,194,304
  const int NW = D_ * D_;          // 1,048,576
  const int NK = B_ * SKM * D_;    // 4,325,376

  unsigned short* ws = (unsigned short*)d_ws;   // ~67.6 MB + 16 KB
  unsigned short* qf = ws;
  unsigned short* kf = qf + NQ;
  unsigned short* vf = kf + NQ;
  unsigned short* wq = vf + NQ;
  unsigned short* wk = wq + NW;
  unsigned short* wv = wk + NW;
  unsigned short* wo = wv + NW;
  unsigned short* Qb = wo + NW;
  unsigned short* Kb = Qb + NQ;
  unsigned short* Vt = Kb + NK;    // [b][h][d][key]
  unsigned short* Xb = Vt + NK;
  int* idx = (int*)(Xb + NQ);      // [B][S]
  int* cnt = idx + B_ * S_;        // [B]

  compact_mask<<<B_, 256, 0, stream>>>(mask, idx, cnt);
  cvt_f32_to_bf16<<<NQ / 1024, 256, 0, stream>>>(query, qf);
  cvt_kv_gather<<<dim3(S_, B_, 2), 256, 0, stream>>>(key, value, kf, vf, idx, cnt);
  cvt_w4<<<dim3(NW / 1024, 4), 256, 0, stream>>>(Wq, Wk, Wv, Wo, wq, wk, wv, wo);

  // merged Q/K/V projection (z selects); K/V halves early-exit via cnt
  gemm_qkv<<<dim3(D_ / 128, (B_ * S_) / 128, 3), 256, 0, stream>>>(
      qf, kf, vf, wq, wk, wv, bq, bk, bv, Qb, Kb, Vt, cnt);
  // memory rows appended at key position cnt[b] — must run AFTER K/V GEMMs
  fill_mem<<<(M_ * D_) / 256, 256, 0, stream>>>(m_k, m_v, Kb, Vt, cnt);

  attn_kernel<<<dim3(S_ / 128, H_, B_), 256, 0, stream>>>(Qb, Kb, Vt, cnt, Xb);

  gemm_o<<<dim3(D_ / 128, (B_ * S_) / 128), 256, 0, stream>>>(Xb, wo, bo, (float*)d_out);
}

// Round 5
// 144.243 us; speedup vs baseline: 2.1447x; 1.0171x over previous
//
#include <hip/hip_runtime.h>
#include <hip/hip_bf16.h>
#include <stdint.h>

// Problem constants (B,S,D,H,M) = (2,2048,1024,16,64), HD=64
#define B_  2
#define S_  2048
#define D_  1024
#define H_  16
#define HD_ 64
#define M_  64
#define SKM (S_ + M_)   // 2112
#define LOG2E 1.44269504088896340736f

typedef __attribute__((ext_vector_type(8))) short s16x8;
typedef __attribute__((ext_vector_type(4))) float f32x4;
typedef __attribute__((ext_vector_type(16))) float f32x16;

// global_load_lds width=16: linear LDS dest (base + lane*16), per-lane global src
#define GLOAD16(gp, lp) __builtin_amdgcn_global_load_lds( \
    (const __attribute__((address_space(1))) void*)(gp),  \
    (__attribute__((address_space(3))) void*)(lp), 16, 0, 0)

__device__ __forceinline__ unsigned short f2bf(float f) {
  union { float f; unsigned int u; } v; v.f = f;
  unsigned int r = v.u + 0x7fffu + ((v.u >> 16) & 1u);  // RNE
  return (unsigned short)(r >> 16);
}

__device__ __forceinline__ unsigned pkbf(float lo, float hi) {
  union { __hip_bfloat162 b; unsigned u; } t;
  t.b = __float22bfloat162_rn(make_float2(lo, hi));   // -> v_cvt_pk_bf16_f32
  return t.u;
}

// ---- mask compaction: idx[b][j] = j-th unmasked key, cnt[b] = count ----------
__global__ void compact_mask(const int* __restrict__ mask,
                             int* __restrict__ idx, int* __restrict__ cnt) {
  const int b = blockIdx.x;
  __shared__ int base, wsum[4];
  if (threadIdx.x == 0) base = 0;
  const int lane = threadIdx.x & 63, w = threadIdx.x >> 6;
  __syncthreads();
  for (int c = 0; c < S_; c += 256) {
    int key = c + threadIdx.x;
    int mv = mask[b * S_ + key];
    unsigned long long bal = __ballot(mv != 0);
    int pre = __popcll(bal & ((1ull << lane) - 1ull));
    if (lane == 0) wsum[w] = __popcll(bal);
    __syncthreads();
    int woff = 0;
    for (int i = 0; i < w; i++) woff += wsum[i];
    int tot = wsum[0] + wsum[1] + wsum[2] + wsum[3];
    if (mv) idx[b * S_ + base + woff + pre] = key;
    __syncthreads();
    if (threadIdx.x == 0) base += tot;
    __syncthreads();
  }
  if (threadIdx.x == 0) cnt[b] = base;
}

// ---------------- f32 -> bf16 conversion (exact-grid, 4 elems/thread) ----------
__global__ void cvt_f32_to_bf16(const float* __restrict__ in,
                                unsigned short* __restrict__ out) {
  int i = (blockIdx.x * blockDim.x + threadIdx.x) * 4;
  float4 v = *(const float4*)&in[i];
  ushort4 o;
  o.x = f2bf(v.x); o.y = f2bf(v.y); o.z = f2bf(v.z); o.w = f2bf(v.w);
  *(ushort4*)&out[i] = o;
}

// ---- 4 weight matrices in one launch (blockIdx.y selects) --------------------
__global__ void cvt_w4(const float* __restrict__ w0, const float* __restrict__ w1,
                       const float* __restrict__ w2, const float* __restrict__ w3,
                       unsigned short* __restrict__ o0, unsigned short* __restrict__ o1,
                       unsigned short* __restrict__ o2, unsigned short* __restrict__ o3) {
  const float* in; unsigned short* out;
  switch (blockIdx.y) {
    case 0: in = w0; out = o0; break;
    case 1: in = w1; out = o1; break;
    case 2: in = w2; out = o2; break;
    default: in = w3; out = o3; break;
  }
  int i = (blockIdx.x * 256 + threadIdx.x) * 4;
  float4 v = *(const float4*)&in[i];
  ushort4 o;
  o.x = f2bf(v.x); o.y = f2bf(v.y); o.z = f2bf(v.z); o.w = f2bf(v.w);
  *(ushort4*)&out[i] = o;
}

// ---- gather-convert key/value rows where mask=1 (one row per block) ----------
__global__ void cvt_kv_gather(const float* __restrict__ key, const float* __restrict__ value,
                              unsigned short* __restrict__ kf, unsigned short* __restrict__ vf,
                              const int* __restrict__ idx, const int* __restrict__ cnt) {
  int b = blockIdx.y, j = blockIdx.x;
  if (j >= cnt[b]) return;
  const float* in = blockIdx.z ? value : key;
  unsigned short* out = blockIdx.z ? vf : kf;
  int src = idx[b * S_ + j];
  const float* ip = in + ((size_t)(b * S_) + src) * D_;
  unsigned short* op = out + ((size_t)(b * S_) + j) * D_;
  int t = threadIdx.x * 4;
  float4 v = *(const float4*)&ip[t];
  ushort4 o;
  o.x = f2bf(v.x); o.y = f2bf(v.y); o.z = f2bf(v.z); o.w = f2bf(v.w);
  *(ushort4*)&op[t] = o;
}

// ---- memory rows appended at key position cnt[b] (AFTER the K/V GEMMs) -------
__global__ void fill_mem(const float* __restrict__ mk, const float* __restrict__ mv,
                         unsigned short* __restrict__ Kb, unsigned short* __restrict__ VtG,
                         const int* __restrict__ cnt) {
  int i = blockIdx.x * 256 + threadIdx.x;     // 0 .. M_*D_-1
  int row = i >> 10, col = i & 1023;
  int hI = col >> 6, dd = col & 63;
  unsigned short kv = f2bf(8.0f * mk[i]);
  unsigned short vv = f2bf(8.0f * mv[i]);
#pragma unroll
  for (int b = 0; b < B_; b++) {
    int c = cnt[b];
    Kb[((size_t)(b * SKM) + c + row) * D_ + col] = kv;
    VtG[((size_t)(b * H_ + hI) * HD_ + dd) * SKM + c + row] = vv;
  }
}

// ------------- GEMM core: 128x128 tile, BK=32, 2-phase double-buffer ----------
// LDS [2][128][32] per matrix (32 KB total). Swizzle: chunk c ^= (row>>1)&3
// (16-lane ds_read_b128 column-read lands 2-way = free). gload_lds writes
// linearly; swizzle applied via inverse-permuted global source (rule #21).
__device__ __forceinline__ void gemm_core2(
    const unsigned short* __restrict__ A,
    const unsigned short* __restrict__ Bw,
    unsigned short* As, unsigned short* Bs,   // each 2*128*32 elems
    int mBase, int nBase, int K,
    int w, int lane, int wr, int wc, int lr, int lk,
    f32x4 acc[4][4]) {
  const int srow = w * 32 + (lane >> 2);    // staging row (gload i adds +16)
  const int cd = lane & 3;                  // dest chunk (linear)
  const int NT = K / 32;

#define STAGE_(buf, k0)                                                          \
  {                                                                              \
    _Pragma("unroll")                                                            \
    for (int i = 0; i < 2; i++) {                                                \
      int r = srow + i * 16;                                                     \
      int ca = cd ^ ((r >> 1) & 3);       /* inverse-swizzled source chunk */    \
      GLOAD16(&A[(size_t)(mBase + r) * K + (k0) + ca * 8],                       \
              &As[(buf) * (128 * 32) + (w * 32 + i * 16) * 32]);                 \
      GLOAD16(&Bw[(size_t)(nBase + r) * K + (k0) + ca * 8],                      \
              &Bs[(buf) * (128 * 32) + (w * 32 + i * 16) * 32]);                 \
    }                                                                            \
  }

  STAGE_(0, 0);
  __syncthreads();                           // drain prologue DMA
  int cur = 0;
  for (int t = 0; t < NT; ++t) {
    if (t + 1 < NT) STAGE_(cur ^ 1, (t + 1) * 32);   // issue BEFORE compute
    s16x8 af[4], bf[4];
#pragma unroll
    for (int mi = 0; mi < 4; mi++) {
      int row = wr * 64 + mi * 16 + lr;
      af[mi] = *(const s16x8*)&As[cur * (128 * 32) + row * 32 + ((lk ^ ((row >> 1) & 3)) << 3)];
    }
#pragma unroll
    for (int ni = 0; ni < 4; ni++) {
      int row = wc * 64 + ni * 16 + lr;
      bf[ni] = *(const s16x8*)&Bs[cur * (128 * 32) + row * 32 + ((lk ^ ((row >> 1) & 3)) << 3)];
    }
#pragma unroll
    for (int mi = 0; mi < 4; mi++)
#pragma unroll
      for (int ni = 0; ni < 4; ni++)
        acc[mi][ni] = __builtin_amdgcn_mfma_f32_16x16x32_bf16(af[mi], bf[ni], acc[mi][ni], 0, 0, 0);
    __syncthreads();   // drains this iter's DMA (vmcnt0) + read-done for cur
    cur ^= 1;
  }
#undef STAGE_
}

// ---- merged Q/K/V projection, 1D grid 768, XCD-chunked work swizzle ----------
__global__ __launch_bounds__(256)
void gemm_qkv(const unsigned short* __restrict__ qf, const unsigned short* __restrict__ kf,
              const unsigned short* __restrict__ vf,
              const unsigned short* __restrict__ wq, const unsigned short* __restrict__ wk,
              const unsigned short* __restrict__ wv,
              const float* __restrict__ bq, const float* __restrict__ bk,
              const float* __restrict__ bv,
              unsigned short* __restrict__ Qb, unsigned short* __restrict__ Kb,
              unsigned short* __restrict__ Vt,
              const int* __restrict__ cnt) {
  __shared__ __align__(16) unsigned short As[2 * 128 * 32];
  __shared__ __align__(16) unsigned short Bs[2 * 128 * 32];
  // T1: within each z-slice of 256 works, XCD (bid&7) owns 32 contiguous works
  // (4 A-panels x full weight ~ 3 MB, fits 4 MB per-XCD L2)
  const int z = blockIdx.x >> 8;
  const int local = blockIdx.x & 255;
  const int ws = (local & 7) * 32 + (local >> 3);   // bijective (256 = 8*32)
  const int nBase = (ws & 7) * 128, mBase = (ws >> 3) * 128;
  if (z) {   // K/V: skip tiles entirely beyond the compacted row count
    int c = (mBase < S_) ? cnt[0] : cnt[1];
    int lo = (mBase < S_) ? mBase : (mBase - S_);
    if (lo >= c) return;
  }
  const unsigned short* A  = (z == 0) ? qf : (z == 1) ? kf : vf;
  const unsigned short* Bw = (z == 0) ? wq : (z == 1) ? wk : wv;
  const float* bias        = (z == 0) ? bq : (z == 1) ? bk : bv;

  const int tid = threadIdx.x, lane = tid & 63;
  const int w = tid >> 6, wr = w >> 1, wc = w & 1;
  const int lr = lane & 15, lk = lane >> 4;

  const f32x4 fz = {0.f, 0.f, 0.f, 0.f};
  f32x4 acc[4][4];
#pragma unroll
  for (int i = 0; i < 4; i++)
#pragma unroll
    for (int j = 0; j < 4; j++) acc[i][j] = fz;

  gemm_core2(A, Bw, As, Bs, mBase, nBase, D_, w, lane, wr, wc, lr, lk, acc);

  const float alpha = (z == 0) ? 0.125f * LOG2E : 1.0f;   // Q: 1/sqrt(HD) * log2(e)
#pragma unroll
  for (int mi = 0; mi < 4; mi++)
#pragma unroll
    for (int ni = 0; ni < 4; ni++)
#pragma unroll
      for (int r = 0; r < 4; r++) {
        int gr = mBase + wr * 64 + mi * 16 + lk * 4 + r;
        int gc = nBase + wc * 64 + ni * 16 + lr;
        float v = (acc[mi][ni][r] + bias[gc]) * alpha;
        if (z == 2) {        // V^T: [b][h][d][key]
          int bb = gr / S_, s = gr - bb * S_;
          int hI = gc >> 6, dd = gc & 63;
          Vt[((size_t)(bb * H_ + hI) * HD_ + dd) * SKM + s] = f2bf(v);
        } else if (z == 1) { // K rows with per-batch mem-row gap
          int orow = gr + (gr / S_) * M_;
          Kb[(size_t)orow * D_ + gc] = f2bf(v);
        } else {
          Qb[(size_t)gr * D_ + gc] = f2bf(v);
        }
      }
}

// ---- output projection: f32 out, 1D grid 256, same swizzle -------------------
__global__ __launch_bounds__(256)
void gemm_o(const unsigned short* __restrict__ A, const unsigned short* __restrict__ Bw,
            const float* __restrict__ bias, float* __restrict__ Cout) {
  __shared__ __align__(16) unsigned short As[2 * 128 * 32];
  __shared__ __align__(16) unsigned short Bs[2 * 128 * 32];
  const int local = blockIdx.x & 255;
  const int ws = (local & 7) * 32 + (local >> 3);
  const int nBase = (ws & 7) * 128, mBase = (ws >> 3) * 128;
  const int tid = threadIdx.x, lane = tid & 63;
  const int w = tid >> 6, wr = w >> 1, wc = w & 1;
  const int lr = lane & 15, lk = lane >> 4;

  const f32x4 fz = {0.f, 0.f, 0.f, 0.f};
  f32x4 acc[4][4];
#pragma unroll
  for (int i = 0; i < 4; i++)
#pragma unroll
    for (int j = 0; j < 4; j++) acc[i][j] = fz;

  gemm_core2(A, Bw, As, Bs, mBase, nBase, D_, w, lane, wr, wc, lr, lk, acc);

#pragma unroll
  for (int mi = 0; mi < 4; mi++)
#pragma unroll
    for (int ni = 0; ni < 4; ni++)
#pragma unroll
      for (int r = 0; r < 4; r++) {
        int gr = mBase + wr * 64 + mi * 16 + lk * 4 + r;
        int gc = nBase + wc * 64 + ni * 16 + lr;
        Cout[(size_t)gr * D_ + gc] = acc[mi][ni][r] + bias[gc];
      }
}

// -------- Flash attention over compacted keys + memory slots ------------------
// Block: 128 q-rows (4 waves x 32) for one (b,h). KV tile = 64 keys.
// Per lane: q = lane&31; P^T in registers; scores in log2 units (LOG2E in Q).
__global__ __launch_bounds__(256)
void attn_kernel(const unsigned short* __restrict__ Qb,
                 const unsigned short* __restrict__ Kb,
                 const unsigned short* __restrict__ VtG,
                 const int* __restrict__ cnt,
                 unsigned short* __restrict__ Xb) {
  __shared__ __align__(16) unsigned short Ks[64 * 64];   // [key][d]  swizzled
  __shared__ __align__(16) unsigned short Vs[64 * 64];   // [d][key]  swizzled

  const int tid = threadIdx.x, lane = tid & 63, w = tid >> 6;
  const int l31 = lane & 31, hh = lane >> 5;
  const int qt = blockIdx.x, h = blockIdx.y, b = blockIdx.z;

  const int total = cnt[b] + M_;            // live keys incl. memory slots
  const int nt = (total + 63) >> 6;         // tiles (<= 33)

  const int r0 = tid >> 3, c0 = tid & 7;          // staging: row, chunk
  const int ck = c0 ^ (r0 & 7);                   // swizzled ((r0+32)&7 == r0&7)
  const unsigned short* Kg = Kb + (size_t)b * SKM * D_ + (size_t)h * HD_;
  const unsigned short* Vg = VtG + (size_t)(b * H_ + h) * HD_ * SKM;

  // Q fragments (B-operand of swapped QK^T): Q[q][ds*16 + hh*8 + i]
  const unsigned short* qp = Qb + ((size_t)(b * S_) + qt * 128 + w * 32 + l31) * D_ + h * HD_;
  s16x8 qf[4];
#pragma unroll
  for (int ds = 0; ds < 4; ds++) qf[ds] = *(const s16x8*)&qp[ds * 16 + hh * 8];

  f32x16 accO[2];
#pragma unroll
  for (int dt = 0; dt < 2; dt++)
#pragma unroll
    for (int j = 0; j < 16; j++) accO[dt][j] = 0.f;
  float m_r = -1e20f, l_r = 0.f;

  uint4 kr0, kr1, vr0, vr1;
  auto LOAD = [&](int kt) {   // rows < nt*64 <= 2112, always in-bounds
    kr0 = *(const uint4*)&Kg[(size_t)(kt * 64 + r0) * D_ + c0 * 8];
    kr1 = *(const uint4*)&Kg[(size_t)(kt * 64 + r0 + 32) * D_ + c0 * 8];
    vr0 = *(const uint4*)&Vg[(size_t)r0 * SKM + kt * 64 + c0 * 8];
    vr1 = *(const uint4*)&Vg[(size_t)(r0 + 32) * SKM + kt * 64 + c0 * 8];
  };
  LOAD(0);

  for (int kt = 0; kt < nt; ++kt) {
    __syncthreads();                 // previous tile's LDS reads complete
    *(uint4*)&Ks[r0 * 64 + ck * 8] = kr0;
    *(uint4*)&Ks[(r0 + 32) * 64 + ck * 8] = kr1;
    *(uint4*)&Vs[r0 * 64 + ck * 8] = vr0;
    *(uint4*)&Vs[(r0 + 32) * 64 + ck * 8] = vr1;
    __syncthreads();
    if (kt + 1 < nt) LOAD(kt + 1);   // prefetch hides HBM under compute

    // ---- S^T = K · Q^T : p0 = keys 0..31, p1 = keys 32..63 (lane: q=l31) ----
    f32x16 p0, p1;
#pragma unroll
    for (int j = 0; j < 16; j++) { p0[j] = 0.f; p1[j] = 0.f; }
#pragma unroll
    for (int ds = 0; ds < 4; ds++) {
      s16x8 ka0 = *(const s16x8*)&Ks[l31 * 64 + (((ds * 2 + hh) ^ (l31 & 7)) << 3)];
      s16x8 ka1 = *(const s16x8*)&Ks[(32 + l31) * 64 + (((ds * 2 + hh) ^ (l31 & 7)) << 3)];
      p0 = __builtin_amdgcn_mfma_f32_32x32x16_bf16(ka0, qf[ds], p0, 0, 0, 0);
      p1 = __builtin_amdgcn_mfma_f32_32x32x16_bf16(ka1, qf[ds], p1, 0, 0, 0);
    }

    // ---- tail tile: kill keys beyond `total` (key = (j&3)+8*(j>>2)+4*hh) ----
    if (kt == nt - 1) {
      int valid = total - kt * 64;   // 1..64
#pragma unroll
      for (int j = 0; j < 16; j++) {
        int kl = (j & 3) + 8 * (j >> 2) + 4 * hh;
        if (kl >= valid) p0[j] = -1e30f;
        if (kl + 32 >= valid) p1[j] = -1e30f;
      }
    }

    // ---- online softmax in log2 units, defer-max (T13, THR=8) ----
    float vmax = fmaxf(p0[0], p1[0]);
#pragma unroll
    for (int j = 1; j < 16; j++) vmax = fmaxf(vmax, fmaxf(p0[j], p1[j]));
    vmax = fmaxf(vmax, __shfl_xor(vmax, 32));
    if (!__all(vmax - m_r <= 8.0f)) {
      float mnew = fmaxf(m_r, vmax);
      float fac = __builtin_amdgcn_exp2f(m_r - mnew);
      m_r = mnew;
      l_r *= fac;
#pragma unroll
      for (int dt = 0; dt < 2; dt++)
#pragma unroll
        for (int j = 0; j < 16; j++) accO[dt][j] *= fac;
    }
    float sum = 0.f;
#pragma unroll
    for (int j = 0; j < 16; j++) {
      p0[j] = __builtin_amdgcn_exp2f(p0[j] - m_r); sum += p0[j];
      p1[j] = __builtin_amdgcn_exp2f(p1[j] - m_r); sum += p1[j];
    }
    sum += __shfl_xor(sum, 32);
    l_r += sum;

    // ---- build P^T fragments: frag[ks] = P[q][16ks + hh*8 + 0..7] as bf16x8 ----
    s16x8 pf_[4];
#pragma unroll
    for (int ks = 0; ks < 4; ks++) {
      const int base = (ks & 1) * 8;
#define ELT(t) ((ks >= 2) ? p1[base + (t)] : p0[base + (t)])
      unsigned w0 = pkbf(ELT(0), ELT(1));
      unsigned w1 = pkbf(ELT(2), ELT(3));
      unsigned w2 = pkbf(ELT(4), ELT(5));
      unsigned w3 = pkbf(ELT(6), ELT(7));
#undef ELT
      unsigned s0 = hh ? w0 : w2;         // h0 sends keys {8..11}, h1 sends {4..7}
      unsigned s1 = hh ? w1 : w3;
      unsigned g0 = (unsigned)__shfl_xor((int)s0, 32);
      unsigned g1 = (unsigned)__shfl_xor((int)s1, 32);
      union { s16x8 v; unsigned u[4]; } pf;
      pf.u[0] = hh ? g0 : w0;
      pf.u[1] = hh ? g1 : w1;
      pf.u[2] = hh ? w2 : g0;
      pf.u[3] = hh ? w3 : g1;
      pf_[ks] = pf.v;
    }

    // ---- O^T += V^T · P^T  (row d = dt*32+(j&3)+8*(j>>2)+4*hh, col q = l31) ----
#pragma unroll
    for (int dt = 0; dt < 2; dt++)
#pragma unroll
      for (int ks = 0; ks < 4; ks++) {
        s16x8 va = *(const s16x8*)&Vs[(dt * 32 + l31) * 64 + (((ks * 2 + hh) ^ (l31 & 7)) << 3)];
        accO[dt] = __builtin_amdgcn_mfma_f32_32x32x16_bf16(va, pf_[ks], accO[dt], 0, 0, 0);
      }
  }

  float invl = 1.0f / l_r;
  size_t orow = ((size_t)(b * S_) + qt * 128 + w * 32 + l31) * D_ + h * HD_;
#pragma unroll
  for (int dt = 0; dt < 2; dt++)
#pragma unroll
    for (int j = 0; j < 16; j++) {
      int d = dt * 32 + (j & 3) + 8 * (j >> 2) + 4 * hh;
      Xb[orow + d] = f2bf(accO[dt][j] * invl);
    }
}

// ------------------------------- launcher -------------------------------------
extern "C" void kernel_launch(void* const* d_in, const int* in_sizes, int n_in,
                              void* d_out, int out_size, void* d_ws, size_t ws_size,
                              hipStream_t stream) {
  const float* query = (const float*)d_in[0];
  const float* key   = (const float*)d_in[1];
  const float* value = (const float*)d_in[2];
  const int*   mask  = (const int*)d_in[3];
  const float* Wq    = (const float*)d_in[4];
  const float* bq    = (const float*)d_in[5];
  const float* Wk    = (const float*)d_in[6];
  const float* bk    = (const float*)d_in[7];
  const float* Wv    = (const float*)d_in[8];
  const float* bv    = (const float*)d_in[9];
  const float* Wo    = (const float*)d_in[10];
  const float* bo    = (const float*)d_in[11];
  const float* m_k   = (const float*)d_in[12];
  const float* m_v   = (const float*)d_in[13];

  const int NQ = B_ * S_ * D_;     // 4,194,304
  const int NW = D_ * D_;          // 1,048,576
  const int NK = B_ * SKM * D_;    // 4,325,376

  unsigned short* ws = (unsigned short*)d_ws;   // ~67.6 MB + 16 KB
  unsigned short* qf = ws;
  unsigned short* kf = qf + NQ;
  unsigned short* vf = kf + NQ;
  unsigned short* wq = vf + NQ;
  unsigned short* wk = wq + NW;
  unsigned short* wv = wk + NW;
  unsigned short* wo = wv + NW;
  unsigned short* Qb = wo + NW;
  unsigned short* Kb = Qb + NQ;
  unsigned short* Vt = Kb + NK;    // [b][h][d][key]
  unsigned short* Xb = Vt + NK;
  int* idx = (int*)(Xb + NQ);      // [B][S]
  int* cnt = idx + B_ * S_;        // [B]

  compact_mask<<<B_, 256, 0, stream>>>(mask, idx, cnt);
  cvt_f32_to_bf16<<<NQ / 1024, 256, 0, stream>>>(query, qf);
  cvt_kv_gather<<<dim3(S_, B_, 2), 256, 0, stream>>>(key, value, kf, vf, idx, cnt);
  cvt_w4<<<dim3(NW / 1024, 4), 256, 0, stream>>>(Wq, Wk, Wv, Wo, wq, wk, wv, wo);

  // merged Q/K/V projection, 1D grid with XCD-chunked swizzle
  gemm_qkv<<<768, 256, 0, stream>>>(qf, kf, vf, wq, wk, wv, bq, bk, bv, Qb, Kb, Vt, cnt);
  // memory rows appended at key position cnt[b] — must run AFTER K/V GEMMs
  fill_mem<<<(M_ * D_) / 256, 256, 0, stream>>>(m_k, m_v, Kb, Vt, cnt);

  attn_kernel<<<dim3(S_ / 128, H_, B_), 256, 0, stream>>>(Qb, Kb, Vt, cnt, Xb);

  gemm_o<<<256, 256, 0, stream>>>(Xb, wo, bo, (float*)d_out);
}